// Round 13
// baseline (554.682 us; speedup 1.0000x reference)
//
#include <hip/hip_runtime.h>

// DecoupleModel: 3x GIN MP layers (split-bf16 MFMA) + CSR-gather aggregation
// + fused output MLP (split-bf16 MFMA).
// R12 = exact revert to R10 (554us verified). R11's fused_out restructure
// spilled (WRITE_SIZE 25MB->948MB, VGPR over budget) and agg half-split
// halved payload/instr + doubled index reads. Both reverted.

typedef __attribute__((ext_vector_type(8))) short short8;
typedef __attribute__((ext_vector_type(4))) float f32x4;
typedef __attribute__((ext_vector_type(8))) _Float16 h16x8;
typedef __attribute__((ext_vector_type(4))) _Float16 h16x4;

constexpr float SQRT2   = 1.41421356237309515f;
constexpr float ONE_EPS = 1.0f + SQRT2;          // (1 + eps)
constexpr float RS      = 0.08838834764831845f;  // 1/sqrt(128)
constexpr int   CH      = 8192;                  // edges per P1/P3 block

__device__ inline unsigned short bf16rne(float f) {
  unsigned int u = __float_as_uint(f);
  return (unsigned short)((u + 0x7FFFu + ((u >> 16) & 1u)) >> 16);
}
__device__ inline float bf16tof(unsigned short h) {
  return __uint_as_float(((unsigned int)h) << 16);
}

// ---------------- graph preprocessing --------------------------------------
__global__ __launch_bounds__(256) void p1_kernel(
    const int* __restrict__ ei, int E, int NB, int NBLK,
    int* __restrict__ bcnt_t, int* __restrict__ bcnt_s) {
  __shared__ int cb[1024], cb2[1024];
  for (int i = threadIdx.x; i < 1024; i += 256) { cb[i] = 0; cb2[i] = 0; }
  __syncthreads();
  const int base = blockIdx.x * CH;
#pragma unroll 4
  for (int it = 0; it < CH / 256; ++it) {
    const int e = base + it * 256 + threadIdx.x;
    if (e < E) {
      atomicAdd(&cb[ei[e] >> 7], 1);
      atomicAdd(&cb2[ei[E + e] >> 7], 1);
    }
  }
  __syncthreads();
  for (int i = threadIdx.x; i < NB; i += 256) {
    bcnt_t[(size_t)i * NBLK + blockIdx.x] = cb[i];
    bcnt_s[(size_t)i * NBLK + blockIdx.x] = cb2[i];
  }
}

__global__ __launch_bounds__(256) void scan_tot(
    const int* __restrict__ bcnt, int* __restrict__ tot, int NBLK, int NB) {
  const int wid = blockIdx.x * 4 + (threadIdx.x >> 6);
  const int lane = threadIdx.x & 63;
  if (wid >= NB) return;
  int s = 0;
  for (int b = lane; b < NBLK; b += 64) s += bcnt[(size_t)wid * NBLK + b];
  for (int o = 32; o > 0; o >>= 1) s += __shfl_down(s, o);
  if (lane == 0) tot[wid] = s;
}

__global__ __launch_bounds__(1024) void scan_base(
    const int* __restrict__ tot, int* __restrict__ barr, int NB, int E,
    int* __restrict__ rowptr, int N) {
  __shared__ int sh[1024];
  const int t = threadIdx.x;
  const int v = (t < NB) ? tot[t] : 0;
  sh[t] = v;
  __syncthreads();
  for (int o = 1; o < 1024; o <<= 1) {
    int u = (t >= o) ? sh[t - o] : 0;
    __syncthreads();
    sh[t] += u;
    __syncthreads();
  }
  if (t < NB) barr[t] = sh[t] - v;
  if (t == 0) { barr[NB] = E; if (rowptr) rowptr[N] = E; }
}

__global__ __launch_bounds__(256) void scan_ofs(
    const int* __restrict__ bcnt, const int* __restrict__ barr,
    int* __restrict__ ofs, int NBLK, int NB) {
  const int wid = blockIdx.x * 4 + (threadIdx.x >> 6);
  const int lane = threadIdx.x & 63;
  if (wid >= NB) return;
  int run = barr[wid];
  for (int c0 = 0; c0 < NBLK; c0 += 64) {
    const int idx = c0 + lane;
    const int v = (idx < NBLK) ? bcnt[(size_t)wid * NBLK + idx] : 0;
    int incl = v;
#pragma unroll
    for (int o = 1; o < 64; o <<= 1) {
      int u = __shfl_up(incl, o);
      if (lane >= o) incl += u;
    }
    if (idx < NBLK) ofs[(size_t)wid * NBLK + idx] = run + incl - v;
    run += __shfl(incl, 63);
  }
}

__global__ __launch_bounds__(256) void p3_kernel(
    const int* __restrict__ ei, int E, int NB, int NBLK,
    const int* __restrict__ ofs_t, const int* __restrict__ ofs_s,
    unsigned long long* __restrict__ sorted, int* __restrict__ ssbin) {
  __shared__ int cur[1024], cur2[1024];
  for (int i = threadIdx.x; i < NB; i += 256) {
    cur[i]  = ofs_t[(size_t)i * NBLK + blockIdx.x];
    cur2[i] = ofs_s[(size_t)i * NBLK + blockIdx.x];
  }
  __syncthreads();
  const int base = blockIdx.x * CH;
  for (int it = 0; it < CH / 256; ++it) {
    const int e = base + it * 256 + threadIdx.x;
    if (e < E) {
      const int tgt = ei[e], src = ei[E + e];
      const int pos = atomicAdd(&cur[tgt >> 7], 1);
      sorted[pos] = ((unsigned long long)(unsigned)tgt << 32) | (unsigned)src;
      const int pos2 = atomicAdd(&cur2[src >> 7], 1);
      ssbin[pos2] = src;
    }
  }
}

__global__ __launch_bounds__(256) void p4_kernel(
    const unsigned long long* __restrict__ sorted, const int* __restrict__ barr,
    int* __restrict__ rowptr, int* __restrict__ ssrc, int N) {
  __shared__ int fcnt[128], fcur[128], sh[128];
  const int B = blockIdx.x, t = threadIdx.x;
  const int lo = barr[B], hi = barr[B + 1];
  if (t < 128) fcnt[t] = 0;
  __syncthreads();
  for (int i = lo + t; i < hi; i += 256)
    atomicAdd(&fcnt[(int)(sorted[i] >> 32) & 127], 1);
  __syncthreads();
  if (t < 128) sh[t] = fcnt[t];
  __syncthreads();
  for (int o = 1; o < 128; o <<= 1) {
    int v = 0;
    if (t < 128 && t >= o) v = sh[t - o];
    __syncthreads();
    if (t < 128) sh[t] += v;
    __syncthreads();
  }
  if (t < 128) {
    const int base = lo + sh[t] - fcnt[t];   // exclusive
    fcur[t] = base;
    const int node = B * 128 + t;
    if (node < N) rowptr[node] = base;
  }
  __syncthreads();
  for (int i = lo + t; i < hi; i += 256) {
    const unsigned long long p = sorted[i];
    const int pos = atomicAdd(&fcur[(int)(p >> 32) & 127], 1);
    ssrc[pos] = (int)(unsigned)(p & 0xffffffffu);
  }
}

__global__ __launch_bounds__(256) void p4b_kernel(
    const int* __restrict__ ssbin, const int* __restrict__ barr_s,
    float* __restrict__ norm, int N) {
  __shared__ int fcnt[128];
  const int B = blockIdx.x, t = threadIdx.x;
  const int lo = barr_s[B], hi = barr_s[B + 1];
  if (t < 128) fcnt[t] = 0;
  __syncthreads();
  for (int i = lo + t; i < hi; i += 256)
    atomicAdd(&fcnt[ssbin[i] & 127], 1);
  __syncthreads();
  if (t < 128) {
    const int node = B * 128 + t;
    if (node < N) norm[node] = ONE_EPS + (float)fcnt[t];
  }
}

// ---------------- weight folding (unchanged, verified) ---------------------
__global__ void combine_kernel(const float* __restrict__ fcW1, const float* __restrict__ fcb1,
                               const float* __restrict__ pW1,  const float* __restrict__ pb1,
                               const float* __restrict__ outW, const float* __restrict__ outb,
                               float* __restrict__ Wc1, float* __restrict__ Wc2,
                               float* __restrict__ bc) {
  int gid = blockIdx.x * blockDim.x + threadIdx.x;
  if (gid < 512 * 64) {
    int k = gid >> 6, j = gid & 63;
    float s = 0.f;
    for (int m = 0; m < 512; ++m) s = fmaf(fcW1[k * 512 + m], outW[m * 64 + j], s);
    Wc1[gid] = s;
  } else if (gid < 512 * 64 + 128 * 64) {
    int t = gid - 512 * 64, k = t >> 6, j = t & 63;
    float s = 0.f;
    for (int m = 0; m < 512; ++m) s = fmaf(pW1[k * 512 + m], outW[m * 64 + j], s);
    Wc2[t] = s;
  } else if (gid < 512 * 64 + 128 * 64 + 64) {
    int j = gid - (512 * 64 + 128 * 64);
    float s = outb[j];
    for (int m = 0; m < 512; ++m) s = fmaf(fcb1[m] + pb1[m], outW[m * 64 + j], s);
    bc[j] = s;
  }
}

__global__ void convw_kernel(const float* __restrict__ fcW0, const float* __restrict__ pW0,
                             const float* __restrict__ Wc1,  const float* __restrict__ Wc2,
                             const float* __restrict__ fcb0, const float* __restrict__ pb0,
                             unsigned short* __restrict__ FW0h, unsigned short* __restrict__ FW0l,
                             unsigned short* __restrict__ PW0h, unsigned short* __restrict__ PW0l,
                             unsigned short* __restrict__ WC1h, unsigned short* __restrict__ WC1l,
                             unsigned short* __restrict__ WC2h, unsigned short* __restrict__ WC2l,
                             float* __restrict__ bsum) {
  int gid = blockIdx.x * blockDim.x + threadIdx.x;
  if (gid < 65536) {
    int e = gid & 7, c = (gid >> 3) & 15, kg = (gid >> 7) & 3, s = (gid >> 9) & 3, t = gid >> 11;
    int k = s * 32 + kg * 8 + e, n = t * 16 + c;
    float f = fcW0[k * 512 + n];
    unsigned short h = bf16rne(f);
    FW0h[gid] = h; FW0l[gid] = bf16rne(f - bf16tof(h));
    f = pW0[k * 512 + n];
    h = bf16rne(f);
    PW0h[gid] = h; PW0l[gid] = bf16rne(f - bf16tof(h));
  } else if (gid < 65536 + 32768) {
    int g = gid - 65536;
    int e = g & 7, c = (g >> 3) & 15, kg = (g >> 7) & 3, s = (g >> 9) & 15, t = g >> 13;
    int k = s * 32 + kg * 8 + e, n = t * 16 + c;
    float f = Wc1[k * 64 + n];
    unsigned short h = bf16rne(f);
    WC1h[g] = h; WC1l[g] = bf16rne(f - bf16tof(h));
  } else if (gid < 65536 + 32768 + 8192) {
    int g = gid - 98304;
    int e = g & 7, c = (g >> 3) & 15, kg = (g >> 7) & 3, s = (g >> 9) & 3, t = (g >> 11) & 3;
    int k = s * 32 + kg * 8 + e, n = t * 16 + c;
    float f = Wc2[k * 64 + n];
    unsigned short h = bf16rne(f);
    WC2h[g] = h; WC2l[g] = bf16rne(f - bf16tof(h));
  } else if (gid < 65536 + 32768 + 8192 + 512) {
    int j = gid - 106496;
    bsum[j] = fcb0[j] + pb0[j];
  }
}

__global__ void convmp_kernel(const float* __restrict__ W0, const float* __restrict__ W1,
                              const float* __restrict__ W2,
                              unsigned short* __restrict__ M0h, unsigned short* __restrict__ M0l,
                              unsigned short* __restrict__ M1h, unsigned short* __restrict__ M1l,
                              unsigned short* __restrict__ M2h, unsigned short* __restrict__ M2l) {
  int gid = blockIdx.x * blockDim.x + threadIdx.x;
  if (gid >= 3 * 16384) return;
  const int m = gid >> 14, g = gid & 16383;
  int e = g & 7, c = (g >> 3) & 15, kg = (g >> 7) & 3, s = (g >> 9) & 3, t = g >> 11;
  int k = s * 32 + kg * 8 + e, n = t * 16 + c;
  const float* W = (m == 0) ? W0 : (m == 1) ? W1 : W2;
  unsigned short* Mh = (m == 0) ? M0h : (m == 1) ? M1h : M2h;
  unsigned short* Ml = (m == 0) ? M0l : (m == 1) ? M1l : M2l;
  float f = W[k * 128 + n];
  unsigned short h = bf16rne(f);
  Mh[g] = h; Ml[g] = bf16rne(f - bf16tof(h));
}

// ---------------- MP layer GEMM, split-bf16 MFMA (verified R5/R9) ----------
__global__ __launch_bounds__(256) void mp_gemm_mfma(
    const float* __restrict__ A,
    const unsigned short* __restrict__ Wh, const unsigned short* __restrict__ Wl,
    const float* __restrict__ bias, const float* __restrict__ norm,
    _Float16* __restrict__ h2h, int nrows)
{
  __shared__ __attribute__((aligned(16))) char smem[33792];
  const int tid  = threadIdx.x;
  const int row0 = blockIdx.x * 64;

  {
    const int m = tid >> 2, q = tid & 3;
    const int gr = row0 + m;
    const int Mt = m >> 4, r16 = m & 15;
#pragma unroll
    for (int it = 0; it < 8; ++it) {
      const int k = it * 16 + q * 4;
      float4 v = make_float4(0.f, 0.f, 0.f, 0.f);
      if (gr < nrows) v = *(const float4*)(A + (size_t)gr * 128 + k);
      const unsigned short h0 = bf16rne(v.x), h1 = bf16rne(v.y);
      const unsigned short h2v = bf16rne(v.z), h3 = bf16rne(v.w);
      const unsigned short l0 = bf16rne(v.x - bf16tof(h0));
      const unsigned short l1 = bf16rne(v.y - bf16tof(h1));
      const unsigned short l2 = bf16rne(v.z - bf16tof(h2v));
      const unsigned short l3 = bf16rne(v.w - bf16tof(h3));
      const int k3 = it * 2 + (q >> 1);
      const int kg = k3 & 3, ks = k3 >> 2;
      const int eb = (q & 1) * 8;
      const int fb = ((Mt * 4 + ks) * 64 + kg * 16 + r16) * 16 + eb;
      *(uint2*)(smem + fb) =
          make_uint2((unsigned)h0 | ((unsigned)h1 << 16), (unsigned)h2v | ((unsigned)h3 << 16));
      *(uint2*)(smem + 16384 + fb) =
          make_uint2((unsigned)l0 | ((unsigned)l1 << 16), (unsigned)l2 | ((unsigned)l3 << 16));
    }
  }
  __syncthreads();

  const int w = tid >> 6, lane = tid & 63;
  f32x4 acc[4][2] = {};

#pragma unroll
  for (int ks = 0; ks < 4; ++ks) {
    short8 bh[2], bl[2];
#pragma unroll
    for (int nt = 0; nt < 2; ++nt) {
      const int t = w * 2 + nt;
      const size_t ofs = (size_t)(t * 4 + ks) * 512 + lane * 8;
      bh[nt] = *(const short8*)(Wh + ofs);
      bl[nt] = *(const short8*)(Wl + ofs);
    }
#pragma unroll
    for (int Mt = 0; Mt < 4; ++Mt) {
      const int fb = ((Mt * 4 + ks) * 64 + lane) * 16;
      short8 hh = *(const short8*)(smem + fb);
      short8 hl = *(const short8*)(smem + 16384 + fb);
#pragma unroll
      for (int nt = 0; nt < 2; ++nt) {
        f32x4 a = acc[Mt][nt];
        a = __builtin_amdgcn_mfma_f32_16x16x32_bf16(hh, bh[nt], a, 0, 0, 0);
        a = __builtin_amdgcn_mfma_f32_16x16x32_bf16(hh, bl[nt], a, 0, 0, 0);
        a = __builtin_amdgcn_mfma_f32_16x16x32_bf16(hl, bh[nt], a, 0, 0, 0);
        acc[Mt][nt] = a;
      }
    }
  }

  __syncthreads();
  float* ob = (float*)smem;
#pragma unroll
  for (int Mt = 0; Mt < 4; ++Mt)
#pragma unroll
    for (int nt = 0; nt < 2; ++nt) {
      const int col = w * 32 + nt * 16 + (lane & 15);
#pragma unroll
      for (int reg = 0; reg < 4; ++reg) {
        const int row = Mt * 16 + (lane >> 4) * 4 + reg;
        ob[row * 132 + col] = acc[Mt][nt][reg];
      }
    }
  __syncthreads();
  {
    const int r = tid >> 2;
    const int gr = row0 + r;
    if (gr < nrows) {
      const float sc = RS / norm[gr];
      const int cb = (tid & 3) * 32;
#pragma unroll
      for (int j = 0; j < 32; j += 4) {
        float4 v = *(const float4*)&ob[r * 132 + cb + j];
        const float4 b = *(const float4*)&bias[cb + j];
        h16x4 pk;
        pk[0] = (_Float16)(fmaxf(v.x + b.x, 0.f) * sc);
        pk[1] = (_Float16)(fmaxf(v.y + b.y, 0.f) * sc);
        pk[2] = (_Float16)(fmaxf(v.z + b.z, 0.f) * sc);
        pk[3] = (_Float16)(fmaxf(v.w + b.w, 0.f) * sc);
        *(h16x4*)(h2h + (size_t)gr * 128 + cb + j) = pk;
      }
    }
  }
}

// out[t] = (1+eps)*h2[t] + sum_{e in CSR[t]} h2[src[e]]   (fp16 gather, fp32 acc)
__global__ __launch_bounds__(256) void agg_kernel(
    const _Float16* __restrict__ h2h, const int* __restrict__ rowptr,
    const int* __restrict__ ssrc, float* __restrict__ out, int N)
{
  const int wv   = (blockIdx.x * 256 + threadIdx.x) >> 6;
  const int lane = threadIdx.x & 63;
  const int node = wv * 4 + (lane >> 4);
  const int col  = (lane & 15) * 8;
  if (node >= N) return;
  float acc[8];
  {
    const h16x8 sv = *(const h16x8*)(h2h + (size_t)node * 128 + col);
#pragma unroll
    for (int j = 0; j < 8; ++j) acc[j] = ONE_EPS * (float)sv[j];
  }
  const int beg = rowptr[node], end = rowptr[node + 1];
  int i = beg;
  for (; i + 1 < end; i += 2) {
    const int s0 = ssrc[i], s1 = ssrc[i + 1];
    const h16x8 v0 = *(const h16x8*)(h2h + (size_t)s0 * 128 + col);
    const h16x8 v1 = *(const h16x8*)(h2h + (size_t)s1 * 128 + col);
#pragma unroll
    for (int j = 0; j < 8; ++j) acc[j] += (float)v0[j] + (float)v1[j];
  }
  if (i < end) {
    const int s = ssrc[i];
    const h16x8 v = *(const h16x8*)(h2h + (size_t)s * 128 + col);
#pragma unroll
    for (int j = 0; j < 8; ++j) acc[j] += (float)v[j];
  }
  f32x4 o0 = {acc[0], acc[1], acc[2], acc[3]};
  f32x4 o1 = {acc[4], acc[5], acc[6], acc[7]};
  __builtin_nontemporal_store(o0, (f32x4*)(out + (size_t)node * 128 + col));
  __builtin_nontemporal_store(o1, (f32x4*)(out + (size_t)node * 128 + col + 4));
}

// ---------------- fused output MLP, split-bf16 MFMA (verified R4) ----------
__global__ __launch_bounds__(256) void fused_out_mfma(
    const float* __restrict__ h,
    const unsigned short* __restrict__ FW0h, const unsigned short* __restrict__ FW0l,
    const unsigned short* __restrict__ PW0h, const unsigned short* __restrict__ PW0l,
    const unsigned short* __restrict__ WC1h, const unsigned short* __restrict__ WC1l,
    const unsigned short* __restrict__ WC2h, const unsigned short* __restrict__ WC2l,
    const float* __restrict__ bsum, const float* __restrict__ bc,
    float* __restrict__ out, int nrows)
{
  __shared__ __attribute__((aligned(16))) char smem[65536];
  const int tid  = threadIdx.x;
  const int row0 = blockIdx.x * 64;

  {
    const int m = tid >> 2, q = tid & 3;
    const int gr = row0 + m;
    const int Mt = m >> 4, r16 = m & 15;
#pragma unroll
    for (int it = 0; it < 8; ++it) {
      const int k  = it * 16 + q * 4;
      float4 v = make_float4(0.f, 0.f, 0.f, 0.f);
      if (gr < nrows) v = *(const float4*)(h + (size_t)gr * 128 + k);
      const unsigned short h0 = bf16rne(v.x), h1 = bf16rne(v.y);
      const unsigned short h2 = bf16rne(v.z), h3 = bf16rne(v.w);
      const unsigned short l0 = bf16rne(v.x - bf16tof(h0));
      const unsigned short l1 = bf16rne(v.y - bf16tof(h1));
      const unsigned short l2 = bf16rne(v.z - bf16tof(h2));
      const unsigned short l3 = bf16rne(v.w - bf16tof(h3));
      const int k3 = it * 2 + (q >> 1);
      const int kg = k3 & 3, ks = k3 >> 2;
      const int eb = (q & 1) * 8;
      const int fb = ((Mt * 4 + ks) * 64 + kg * 16 + r16) * 16 + eb;
      *(uint2*)(smem + fb) =
          make_uint2((unsigned)h0 | ((unsigned)h1 << 16), (unsigned)h2 | ((unsigned)h3 << 16));
      *(uint2*)(smem + 16384 + fb) =
          make_uint2((unsigned)l0 | ((unsigned)l1 << 16), (unsigned)l2 | ((unsigned)l3 << 16));
    }
  }
  __syncthreads();

  const int w = tid >> 6, lane = tid & 63;
  union U8 { short8 s; unsigned int u[4]; };

  f32x4 oacc[4][4] = {};

  for (int sc = 0; sc < 4; ++sc) {
    f32x4 zacc[4][2] = {};
#pragma unroll
    for (int ks = 0; ks < 4; ++ks) {
      short8 w0h[2], w0l[2], p0h[2], p0l[2];
#pragma unroll
      for (int nt = 0; nt < 2; ++nt) {
        const int t = w * 8 + sc * 2 + nt;
        const size_t ofs = (size_t)(t * 4 + ks) * 512 + lane * 8;
        w0h[nt] = *(const short8*)(FW0h + ofs);
        w0l[nt] = *(const short8*)(FW0l + ofs);
        p0h[nt] = *(const short8*)(PW0h + ofs);
        p0l[nt] = *(const short8*)(PW0l + ofs);
      }
#pragma unroll
      for (int Mt = 0; Mt < 4; ++Mt) {
        const int fb = ((Mt * 4 + ks) * 64 + lane) * 16;
        U8 hh, hl, rh, rl;
        hh.s = *(const short8*)(smem + fb);
        hl.s = *(const short8*)(smem + 16384 + fb);
#pragma unroll
        for (int u = 0; u < 4; ++u) {
          unsigned int msk = ((hh.u[u] & 0x80008000u) >> 15) * 0xFFFFu;
          rh.u[u] = hh.u[u] & ~msk;
          rl.u[u] = hl.u[u] & ~msk;
        }
#pragma unroll
        for (int nt = 0; nt < 2; ++nt) {
          f32x4 a = zacc[Mt][nt];
          a = __builtin_amdgcn_mfma_f32_16x16x32_bf16(rh.s, w0h[nt], a, 0, 0, 0);
          a = __builtin_amdgcn_mfma_f32_16x16x32_bf16(rh.s, w0l[nt], a, 0, 0, 0);
          a = __builtin_amdgcn_mfma_f32_16x16x32_bf16(rl.s, w0h[nt], a, 0, 0, 0);
          a = __builtin_amdgcn_mfma_f32_16x16x32_bf16(hh.s, p0h[nt], a, 0, 0, 0);
          a = __builtin_amdgcn_mfma_f32_16x16x32_bf16(hh.s, p0l[nt], a, 0, 0, 0);
          a = __builtin_amdgcn_mfma_f32_16x16x32_bf16(hl.s, p0h[nt], a, 0, 0, 0);
          zacc[Mt][nt] = a;
        }
      }
    }
    const float bs0 = bsum[w * 128 + sc * 32 + (lane & 15)];
    const float bs1 = bsum[w * 128 + sc * 32 + 16 + (lane & 15)];
#pragma unroll
    for (int Mt = 0; Mt < 4; ++Mt) {
#pragma unroll
      for (int nt = 0; nt < 2; ++nt) {
        const float bs = nt ? bs1 : bs0;
        const int kg = nt * 2 + ((lane >> 3) & 1);
        const int eb = (lane & 7) * 2;
#pragma unroll
        for (int reg = 0; reg < 4; ++reg) {
          const float zv = fmaxf(zacc[Mt][nt][reg] + bs, 0.f);
          const unsigned short zhi = bf16rne(zv);
          const unsigned short zlo = bf16rne(zv - bf16tof(zhi));
          const int r16 = (lane >> 4) * 4 + reg;
          const int fb = ((w * 4 + Mt) * 64 + kg * 16 + r16) * 16 + eb;
          *(unsigned short*)(smem + 32768 + fb) = zhi;
          *(unsigned short*)(smem + 49152 + fb) = zlo;
        }
      }
    }
    asm volatile("s_waitcnt lgkmcnt(0)" ::: "memory");
    const int s2 = w * 4 + sc;
    short8 c1h[4], c1l[4];
#pragma unroll
    for (int t2 = 0; t2 < 4; ++t2) {
      const size_t ofs = (size_t)(t2 * 16 + s2) * 512 + lane * 8;
      c1h[t2] = *(const short8*)(WC1h + ofs);
      c1l[t2] = *(const short8*)(WC1l + ofs);
    }
#pragma unroll
    for (int Mt = 0; Mt < 4; ++Mt) {
      const int fb = ((w * 4 + Mt) * 64 + lane) * 16;
      short8 zh8 = *(const short8*)(smem + 32768 + fb);
      short8 zl8 = *(const short8*)(smem + 49152 + fb);
#pragma unroll
      for (int t2 = 0; t2 < 4; ++t2) {
        f32x4 a = oacc[Mt][t2];
        a = __builtin_amdgcn_mfma_f32_16x16x32_bf16(zh8, c1h[t2], a, 0, 0, 0);
        a = __builtin_amdgcn_mfma_f32_16x16x32_bf16(zh8, c1l[t2], a, 0, 0, 0);
        a = __builtin_amdgcn_mfma_f32_16x16x32_bf16(zl8, c1h[t2], a, 0, 0, 0);
        oacc[Mt][t2] = a;
      }
    }
  }

  {
    short8 c2h[4], c2l[4];
#pragma unroll
    for (int t = 0; t < 4; ++t) {
      const size_t ofs = (size_t)(t * 4 + w) * 512 + lane * 8;
      c2h[t] = *(const short8*)(WC2h + ofs);
      c2l[t] = *(const short8*)(WC2l + ofs);
    }
#pragma unroll
    for (int Mt = 0; Mt < 4; ++Mt) {
      const int fb = ((Mt * 4 + w) * 64 + lane) * 16;
      short8 hh = *(const short8*)(smem + fb);
      short8 hl = *(const short8*)(smem + 16384 + fb);
#pragma unroll
      for (int t = 0; t < 4; ++t) {
        f32x4 a = oacc[Mt][t];
        a = __builtin_amdgcn_mfma_f32_16x16x32_bf16(hh, c2h[t], a, 0, 0, 0);
        a = __builtin_amdgcn_mfma_f32_16x16x32_bf16(hh, c2l[t], a, 0, 0, 0);
        a = __builtin_amdgcn_mfma_f32_16x16x32_bf16(hl, c2h[t], a, 0, 0, 0);
        oacc[Mt][t] = a;
      }
    }
  }

  __syncthreads();
  float* red = (float*)smem;
#pragma unroll
  for (int Mt = 0; Mt < 4; ++Mt)
#pragma unroll
    for (int Nt = 0; Nt < 4; ++Nt)
#pragma unroll
      for (int reg = 0; reg < 4; ++reg) {
        const int row = Mt * 16 + (lane >> 4) * 4 + reg;
        const int col = Nt * 16 + (lane & 15);
        red[(w * 64 + row) * 64 + col] = oacc[Mt][Nt][reg];
      }
  __syncthreads();
  {
    const int c4 = (tid & 15) * 4;
    const int rb = tid >> 4;
    const float4 bcv = *(const float4*)(bc + c4);
#pragma unroll
    for (int rr = 0; rr < 4; ++rr) {
      const int r = rr * 16 + rb;
      const int gr = row0 + r;
      if (gr < nrows) {
        float4 s = bcv;
#pragma unroll
        for (int wv = 0; wv < 4; ++wv) {
          const float4 p = *(const float4*)&red[(wv * 64 + r) * 64 + c4];
          s.x += p.x; s.y += p.y; s.z += p.z; s.w += p.w;
        }
        *(float4*)(out + (size_t)gr * 64 + c4) = s;
      }
    }
  }
}

// ---------------------------------------------------------------------------
extern "C" void kernel_launch(void* const* d_in, const int* in_sizes, int n_in,
                              void* d_out, int out_size, void* d_ws, size_t ws_size,
                              hipStream_t stream) {
  const float* x    = (const float*)d_in[0];
  const int*   ei   = (const int*)d_in[1];   // [2][E] int32
  const float* mpW0 = (const float*)d_in[2];
  const float* mpb0 = (const float*)d_in[3];
  const float* mpW1 = (const float*)d_in[4];
  const float* mpb1 = (const float*)d_in[5];
  const float* mpW2 = (const float*)d_in[6];
  const float* mpb2 = (const float*)d_in[7];
  const float* fcW0 = (const float*)d_in[8];
  const float* fcb0 = (const float*)d_in[9];
  const float* fcW1 = (const float*)d_in[10];
  const float* fcb1 = (const float*)d_in[11];
  const float* pW0  = (const float*)d_in[12];
  const float* pb0  = (const float*)d_in[13];
  const float* pW1  = (const float*)d_in[14];
  const float* pb1  = (const float*)d_in[15];
  const float* outW = (const float*)d_in[16];
  const float* outb = (const float*)d_in[17];

  const int N = in_sizes[0] / 128;
  const int E = in_sizes[1] / 2;
  const int NB   = (N + 127) / 128;          // coarse buckets (<=1024)
  const int NBLK = (E + CH - 1) / CH;        // P1/P3 blocks

  char* ws = (char*)d_ws;
  size_t off = 0;
  auto alloc = [&](size_t bytes) -> char* {
    char* p = ws + off;
    off += (bytes + 255) & ~(size_t)255;
    return p;
  };
  float* norm   = (float*)alloc((size_t)N * 4);
  int*   rowptr = (int*)alloc((size_t)(N + 1) * 4);
  int*   bcnt_t = (int*)alloc((size_t)NB * NBLK * 4);
  int*   bcnt_s = (int*)alloc((size_t)NB * NBLK * 4);
  int*   ofs_t  = (int*)alloc((size_t)NB * NBLK * 4);
  int*   ofs_s  = (int*)alloc((size_t)NB * NBLK * 4);
  int*   tot_t  = (int*)alloc((size_t)NB * 4);
  int*   tot_s  = (int*)alloc((size_t)NB * 4);
  int*   barr_t = (int*)alloc((size_t)(NB + 1) * 4);
  int*   barr_s = (int*)alloc((size_t)(NB + 1) * 4);
  int*   ssrc   = (int*)alloc((size_t)E * 4);
  int*   ssbin  = (int*)alloc((size_t)E * 4);
  unsigned long long* sorted = (unsigned long long*)alloc((size_t)E * 8);
  _Float16* h2h = (_Float16*)alloc((size_t)N * 128 * 2);
  float* hbuf   = (float*)alloc((size_t)N * 128 * 4);
  float* Wc1    = (float*)alloc(512 * 64 * 4);
  float* Wc2    = (float*)alloc(128 * 64 * 4);
  float* bc     = (float*)alloc(64 * 4);
  unsigned short* FW0h = (unsigned short*)alloc(65536 * 2);
  unsigned short* FW0l = (unsigned short*)alloc(65536 * 2);
  unsigned short* PW0h = (unsigned short*)alloc(65536 * 2);
  unsigned short* PW0l = (unsigned short*)alloc(65536 * 2);
  unsigned short* WC1h = (unsigned short*)alloc(32768 * 2);
  unsigned short* WC1l = (unsigned short*)alloc(32768 * 2);
  unsigned short* WC2h = (unsigned short*)alloc(8192 * 2);
  unsigned short* WC2l = (unsigned short*)alloc(8192 * 2);
  float* bsum   = (float*)alloc(512 * 4);
  unsigned short* M0h = (unsigned short*)alloc(16384 * 2);
  unsigned short* M0l = (unsigned short*)alloc(16384 * 2);
  unsigned short* M1h = (unsigned short*)alloc(16384 * 2);
  unsigned short* M1l = (unsigned short*)alloc(16384 * 2);
  unsigned short* M2h = (unsigned short*)alloc(16384 * 2);
  unsigned short* M2l = (unsigned short*)alloc(16384 * 2);
  // total ~= 120 MiB

  const int scblocks = (NB + 3) / 4;

  p1_kernel<<<NBLK, 256, 0, stream>>>(ei, E, NB, NBLK, bcnt_t, bcnt_s);
  scan_tot<<<scblocks, 256, 0, stream>>>(bcnt_t, tot_t, NBLK, NB);
  scan_tot<<<scblocks, 256, 0, stream>>>(bcnt_s, tot_s, NBLK, NB);
  scan_base<<<1, 1024, 0, stream>>>(tot_t, barr_t, NB, E, rowptr, N);
  scan_base<<<1, 1024, 0, stream>>>(tot_s, barr_s, NB, E, nullptr, 0);
  scan_ofs<<<scblocks, 256, 0, stream>>>(bcnt_t, barr_t, ofs_t, NBLK, NB);
  scan_ofs<<<scblocks, 256, 0, stream>>>(bcnt_s, barr_s, ofs_s, NBLK, NB);
  p3_kernel<<<NBLK, 256, 0, stream>>>(ei, E, NB, NBLK, ofs_t, ofs_s, sorted, ssbin);
  p4_kernel<<<NB, 256, 0, stream>>>(sorted, barr_t, rowptr, ssrc, N);
  p4b_kernel<<<NB, 256, 0, stream>>>(ssbin, barr_s, norm, N);
  combine_kernel<<<(512 * 64 + 128 * 64 + 64 + 255) / 256, 256, 0, stream>>>(
      fcW1, fcb1, pW1, pb1, outW, outb, Wc1, Wc2, bc);
  convw_kernel<<<(65536 + 32768 + 8192 + 512 + 255) / 256, 256, 0, stream>>>(
      fcW0, pW0, Wc1, Wc2, fcb0, pb0,
      FW0h, FW0l, PW0h, PW0l, WC1h, WC1l, WC2h, WC2l, bsum);
  convmp_kernel<<<(3 * 16384 + 255) / 256, 256, 0, stream>>>(
      mpW0, mpW1, mpW2, M0h, M0l, M1h, M1l, M2h, M2l);

  const int gx = (N + 63) / 64;
  const int ablocks = (N + 15) / 16;   // 4 waves/block, 4 nodes/wave

  mp_gemm_mfma<<<gx, 256, 0, stream>>>(x,    M0h, M0l, mpb0, norm, h2h, N);
  agg_kernel<<<ablocks, 256, 0, stream>>>(h2h, rowptr, ssrc, hbuf, N);
  mp_gemm_mfma<<<gx, 256, 0, stream>>>(hbuf, M1h, M1l, mpb1, norm, h2h, N);
  agg_kernel<<<ablocks, 256, 0, stream>>>(h2h, rowptr, ssrc, hbuf, N);
  mp_gemm_mfma<<<gx, 256, 0, stream>>>(hbuf, M2h, M2l, mpb2, norm, h2h, N);
  agg_kernel<<<ablocks, 256, 0, stream>>>(h2h, rowptr, ssrc, hbuf, N);

  fused_out_mfma<<<gx, 256, 0, stream>>>(
      hbuf, FW0h, FW0l, PW0h, PW0l, WC1h, WC1l, WC2h, WC2l, bsum, bc,
      (float*)d_out, N);
}

// Round 14
// 550.341 us; speedup vs baseline: 1.0079x; 1.0079x over previous
//
#include <hip/hip_runtime.h>

// DecoupleModel: 3x GIN MP layers (split-bf16 MFMA) + CSR-gather aggregation
// + fused output MLP (split-bf16 MFMA).
// R14: agg stores pre-split bf16 hi/lo in tile-frag-linear layout (hbuf gone;
//      bit-identical values). mp_gemm layers 1/2 read A-frags straight from
//      global (no staging/conversion). fused_out staging = flat memcpy.
//      CH 8192->4096 for p3 occupancy.

typedef __attribute__((ext_vector_type(8))) short short8;
typedef __attribute__((ext_vector_type(4))) float f32x4;
typedef __attribute__((ext_vector_type(8))) _Float16 h16x8;
typedef __attribute__((ext_vector_type(4))) _Float16 h16x4;

constexpr float SQRT2   = 1.41421356237309515f;
constexpr float ONE_EPS = 1.0f + SQRT2;          // (1 + eps)
constexpr float RS      = 0.08838834764831845f;  // 1/sqrt(128)
constexpr int   CH      = 4096;                  // edges per P1/P3 block

__device__ inline unsigned short bf16rne(float f) {
  unsigned int u = __float_as_uint(f);
  return (unsigned short)((u + 0x7FFFu + ((u >> 16) & 1u)) >> 16);
}
__device__ inline float bf16tof(unsigned short h) {
  return __uint_as_float(((unsigned int)h) << 16);
}

// ---------------- graph preprocessing --------------------------------------
__global__ __launch_bounds__(256) void p1_kernel(
    const int* __restrict__ ei, int E, int NB, int NBLK,
    int* __restrict__ bcnt_t, int* __restrict__ bcnt_s) {
  __shared__ int cb[1024], cb2[1024];
  for (int i = threadIdx.x; i < 1024; i += 256) { cb[i] = 0; cb2[i] = 0; }
  __syncthreads();
  const int base = blockIdx.x * CH;
#pragma unroll 4
  for (int it = 0; it < CH / 256; ++it) {
    const int e = base + it * 256 + threadIdx.x;
    if (e < E) {
      atomicAdd(&cb[ei[e] >> 7], 1);
      atomicAdd(&cb2[ei[E + e] >> 7], 1);
    }
  }
  __syncthreads();
  for (int i = threadIdx.x; i < NB; i += 256) {
    bcnt_t[(size_t)i * NBLK + blockIdx.x] = cb[i];
    bcnt_s[(size_t)i * NBLK + blockIdx.x] = cb2[i];
  }
}

__global__ __launch_bounds__(256) void scan_tot(
    const int* __restrict__ bcnt, int* __restrict__ tot, int NBLK, int NB) {
  const int wid = blockIdx.x * 4 + (threadIdx.x >> 6);
  const int lane = threadIdx.x & 63;
  if (wid >= NB) return;
  int s = 0;
  for (int b = lane; b < NBLK; b += 64) s += bcnt[(size_t)wid * NBLK + b];
  for (int o = 32; o > 0; o >>= 1) s += __shfl_down(s, o);
  if (lane == 0) tot[wid] = s;
}

__global__ __launch_bounds__(1024) void scan_base(
    const int* __restrict__ tot, int* __restrict__ barr, int NB, int E,
    int* __restrict__ rowptr, int N) {
  __shared__ int sh[1024];
  const int t = threadIdx.x;
  const int v = (t < NB) ? tot[t] : 0;
  sh[t] = v;
  __syncthreads();
  for (int o = 1; o < 1024; o <<= 1) {
    int u = (t >= o) ? sh[t - o] : 0;
    __syncthreads();
    sh[t] += u;
    __syncthreads();
  }
  if (t < NB) barr[t] = sh[t] - v;
  if (t == 0) { barr[NB] = E; if (rowptr) rowptr[N] = E; }
}

__global__ __launch_bounds__(256) void scan_ofs(
    const int* __restrict__ bcnt, const int* __restrict__ barr,
    int* __restrict__ ofs, int NBLK, int NB) {
  const int wid = blockIdx.x * 4 + (threadIdx.x >> 6);
  const int lane = threadIdx.x & 63;
  if (wid >= NB) return;
  int run = barr[wid];
  for (int c0 = 0; c0 < NBLK; c0 += 64) {
    const int idx = c0 + lane;
    const int v = (idx < NBLK) ? bcnt[(size_t)wid * NBLK + idx] : 0;
    int incl = v;
#pragma unroll
    for (int o = 1; o < 64; o <<= 1) {
      int u = __shfl_up(incl, o);
      if (lane >= o) incl += u;
    }
    if (idx < NBLK) ofs[(size_t)wid * NBLK + idx] = run + incl - v;
    run += __shfl(incl, 63);
  }
}

__global__ __launch_bounds__(256) void p3_kernel(
    const int* __restrict__ ei, int E, int NB, int NBLK,
    const int* __restrict__ ofs_t, const int* __restrict__ ofs_s,
    unsigned long long* __restrict__ sorted, int* __restrict__ ssbin) {
  __shared__ int cur[1024], cur2[1024];
  for (int i = threadIdx.x; i < NB; i += 256) {
    cur[i]  = ofs_t[(size_t)i * NBLK + blockIdx.x];
    cur2[i] = ofs_s[(size_t)i * NBLK + blockIdx.x];
  }
  __syncthreads();
  const int base = blockIdx.x * CH;
  for (int it = 0; it < CH / 256; ++it) {
    const int e = base + it * 256 + threadIdx.x;
    if (e < E) {
      const int tgt = ei[e], src = ei[E + e];
      const int pos = atomicAdd(&cur[tgt >> 7], 1);
      sorted[pos] = ((unsigned long long)(unsigned)tgt << 32) | (unsigned)src;
      const int pos2 = atomicAdd(&cur2[src >> 7], 1);
      ssbin[pos2] = src;
    }
  }
}

__global__ __launch_bounds__(256) void p4_kernel(
    const unsigned long long* __restrict__ sorted, const int* __restrict__ barr,
    int* __restrict__ rowptr, int* __restrict__ ssrc, int N) {
  __shared__ int fcnt[128], fcur[128], sh[128];
  const int B = blockIdx.x, t = threadIdx.x;
  const int lo = barr[B], hi = barr[B + 1];
  if (t < 128) fcnt[t] = 0;
  __syncthreads();
  for (int i = lo + t; i < hi; i += 256)
    atomicAdd(&fcnt[(int)(sorted[i] >> 32) & 127], 1);
  __syncthreads();
  if (t < 128) sh[t] = fcnt[t];
  __syncthreads();
  for (int o = 1; o < 128; o <<= 1) {
    int v = 0;
    if (t < 128 && t >= o) v = sh[t - o];
    __syncthreads();
    if (t < 128) sh[t] += v;
    __syncthreads();
  }
  if (t < 128) {
    const int base = lo + sh[t] - fcnt[t];   // exclusive
    fcur[t] = base;
    const int node = B * 128 + t;
    if (node < N) rowptr[node] = base;
  }
  __syncthreads();
  for (int i = lo + t; i < hi; i += 256) {
    const unsigned long long p = sorted[i];
    const int pos = atomicAdd(&fcur[(int)(p >> 32) & 127], 1);
    ssrc[pos] = (int)(unsigned)(p & 0xffffffffu);
  }
}

__global__ __launch_bounds__(256) void p4b_kernel(
    const int* __restrict__ ssbin, const int* __restrict__ barr_s,
    float* __restrict__ norm, int N) {
  __shared__ int fcnt[128];
  const int B = blockIdx.x, t = threadIdx.x;
  const int lo = barr_s[B], hi = barr_s[B + 1];
  if (t < 128) fcnt[t] = 0;
  __syncthreads();
  for (int i = lo + t; i < hi; i += 256)
    atomicAdd(&fcnt[ssbin[i] & 127], 1);
  __syncthreads();
  if (t < 128) {
    const int node = B * 128 + t;
    if (node < N) norm[node] = ONE_EPS + (float)fcnt[t];
  }
}

// ---------------- weight folding (unchanged, verified) ---------------------
__global__ void combine_kernel(const float* __restrict__ fcW1, const float* __restrict__ fcb1,
                               const float* __restrict__ pW1,  const float* __restrict__ pb1,
                               const float* __restrict__ outW, const float* __restrict__ outb,
                               float* __restrict__ Wc1, float* __restrict__ Wc2,
                               float* __restrict__ bc) {
  int gid = blockIdx.x * blockDim.x + threadIdx.x;
  if (gid < 512 * 64) {
    int k = gid >> 6, j = gid & 63;
    float s = 0.f;
    for (int m = 0; m < 512; ++m) s = fmaf(fcW1[k * 512 + m], outW[m * 64 + j], s);
    Wc1[gid] = s;
  } else if (gid < 512 * 64 + 128 * 64) {
    int t = gid - 512 * 64, k = t >> 6, j = t & 63;
    float s = 0.f;
    for (int m = 0; m < 512; ++m) s = fmaf(pW1[k * 512 + m], outW[m * 64 + j], s);
    Wc2[t] = s;
  } else if (gid < 512 * 64 + 128 * 64 + 64) {
    int j = gid - (512 * 64 + 128 * 64);
    float s = outb[j];
    for (int m = 0; m < 512; ++m) s = fmaf(fcb1[m] + pb1[m], outW[m * 64 + j], s);
    bc[j] = s;
  }
}

__global__ void convw_kernel(const float* __restrict__ fcW0, const float* __restrict__ pW0,
                             const float* __restrict__ Wc1,  const float* __restrict__ Wc2,
                             const float* __restrict__ fcb0, const float* __restrict__ pb0,
                             unsigned short* __restrict__ FW0h, unsigned short* __restrict__ FW0l,
                             unsigned short* __restrict__ PW0h, unsigned short* __restrict__ PW0l,
                             unsigned short* __restrict__ WC1h, unsigned short* __restrict__ WC1l,
                             unsigned short* __restrict__ WC2h, unsigned short* __restrict__ WC2l,
                             float* __restrict__ bsum) {
  int gid = blockIdx.x * blockDim.x + threadIdx.x;
  if (gid < 65536) {
    int e = gid & 7, c = (gid >> 3) & 15, kg = (gid >> 7) & 3, s = (gid >> 9) & 3, t = gid >> 11;
    int k = s * 32 + kg * 8 + e, n = t * 16 + c;
    float f = fcW0[k * 512 + n];
    unsigned short h = bf16rne(f);
    FW0h[gid] = h; FW0l[gid] = bf16rne(f - bf16tof(h));
    f = pW0[k * 512 + n];
    h = bf16rne(f);
    PW0h[gid] = h; PW0l[gid] = bf16rne(f - bf16tof(h));
  } else if (gid < 65536 + 32768) {
    int g = gid - 65536;
    int e = g & 7, c = (g >> 3) & 15, kg = (g >> 7) & 3, s = (g >> 9) & 15, t = g >> 13;
    int k = s * 32 + kg * 8 + e, n = t * 16 + c;
    float f = Wc1[k * 64 + n];
    unsigned short h = bf16rne(f);
    WC1h[g] = h; WC1l[g] = bf16rne(f - bf16tof(h));
  } else if (gid < 65536 + 32768 + 8192) {
    int g = gid - 98304;
    int e = g & 7, c = (g >> 3) & 15, kg = (g >> 7) & 3, s = (g >> 9) & 3, t = (g >> 11) & 3;
    int k = s * 32 + kg * 8 + e, n = t * 16 + c;
    float f = Wc2[k * 64 + n];
    unsigned short h = bf16rne(f);
    WC2h[g] = h; WC2l[g] = bf16rne(f - bf16tof(h));
  } else if (gid < 65536 + 32768 + 8192 + 512) {
    int j = gid - 106496;
    bsum[j] = fcb0[j] + pb0[j];
  }
}

__global__ void convmp_kernel(const float* __restrict__ W0, const float* __restrict__ W1,
                              const float* __restrict__ W2,
                              unsigned short* __restrict__ M0h, unsigned short* __restrict__ M0l,
                              unsigned short* __restrict__ M1h, unsigned short* __restrict__ M1l,
                              unsigned short* __restrict__ M2h, unsigned short* __restrict__ M2l) {
  int gid = blockIdx.x * blockDim.x + threadIdx.x;
  if (gid >= 3 * 16384) return;
  const int m = gid >> 14, g = gid & 16383;
  int e = g & 7, c = (g >> 3) & 15, kg = (g >> 7) & 3, s = (g >> 9) & 3, t = g >> 11;
  int k = s * 32 + kg * 8 + e, n = t * 16 + c;
  const float* W = (m == 0) ? W0 : (m == 1) ? W1 : W2;
  unsigned short* Mh = (m == 0) ? M0h : (m == 1) ? M1h : M2h;
  unsigned short* Ml = (m == 0) ? M0l : (m == 1) ? M1l : M2l;
  float f = W[k * 128 + n];
  unsigned short h = bf16rne(f);
  Mh[g] = h; Ml[g] = bf16rne(f - bf16tof(h));
}

// ---------------- MP layer 0 GEMM (fp32 input x, verified R5/R9) -----------
__global__ __launch_bounds__(256) void mp_gemm_mfma(
    const float* __restrict__ A,
    const unsigned short* __restrict__ Wh, const unsigned short* __restrict__ Wl,
    const float* __restrict__ bias, const float* __restrict__ norm,
    _Float16* __restrict__ h2h, int nrows)
{
  __shared__ __attribute__((aligned(16))) char smem[33792];
  const int tid  = threadIdx.x;
  const int row0 = blockIdx.x * 64;

  {
    const int m = tid >> 2, q = tid & 3;
    const int gr = row0 + m;
    const int Mt = m >> 4, r16 = m & 15;
#pragma unroll
    for (int it = 0; it < 8; ++it) {
      const int k = it * 16 + q * 4;
      float4 v = make_float4(0.f, 0.f, 0.f, 0.f);
      if (gr < nrows) v = *(const float4*)(A + (size_t)gr * 128 + k);
      const unsigned short h0 = bf16rne(v.x), h1 = bf16rne(v.y);
      const unsigned short h2v = bf16rne(v.z), h3 = bf16rne(v.w);
      const unsigned short l0 = bf16rne(v.x - bf16tof(h0));
      const unsigned short l1 = bf16rne(v.y - bf16tof(h1));
      const unsigned short l2 = bf16rne(v.z - bf16tof(h2v));
      const unsigned short l3 = bf16rne(v.w - bf16tof(h3));
      const int k3 = it * 2 + (q >> 1);
      const int kg = k3 & 3, ks = k3 >> 2;
      const int eb = (q & 1) * 8;
      const int fb = ((Mt * 4 + ks) * 64 + kg * 16 + r16) * 16 + eb;
      *(uint2*)(smem + fb) =
          make_uint2((unsigned)h0 | ((unsigned)h1 << 16), (unsigned)h2v | ((unsigned)h3 << 16));
      *(uint2*)(smem + 16384 + fb) =
          make_uint2((unsigned)l0 | ((unsigned)l1 << 16), (unsigned)l2 | ((unsigned)l3 << 16));
    }
  }
  __syncthreads();

  const int w = tid >> 6, lane = tid & 63;
  f32x4 acc[4][2] = {};

#pragma unroll
  for (int ks = 0; ks < 4; ++ks) {
    short8 bh[2], bl[2];
#pragma unroll
    for (int nt = 0; nt < 2; ++nt) {
      const int t = w * 2 + nt;
      const size_t ofs = (size_t)(t * 4 + ks) * 512 + lane * 8;
      bh[nt] = *(const short8*)(Wh + ofs);
      bl[nt] = *(const short8*)(Wl + ofs);
    }
#pragma unroll
    for (int Mt = 0; Mt < 4; ++Mt) {
      const int fb = ((Mt * 4 + ks) * 64 + lane) * 16;
      short8 hh = *(const short8*)(smem + fb);
      short8 hl = *(const short8*)(smem + 16384 + fb);
#pragma unroll
      for (int nt = 0; nt < 2; ++nt) {
        f32x4 a = acc[Mt][nt];
        a = __builtin_amdgcn_mfma_f32_16x16x32_bf16(hh, bh[nt], a, 0, 0, 0);
        a = __builtin_amdgcn_mfma_f32_16x16x32_bf16(hh, bl[nt], a, 0, 0, 0);
        a = __builtin_amdgcn_mfma_f32_16x16x32_bf16(hl, bh[nt], a, 0, 0, 0);
        acc[Mt][nt] = a;
      }
    }
  }

  __syncthreads();
  float* ob = (float*)smem;
#pragma unroll
  for (int Mt = 0; Mt < 4; ++Mt)
#pragma unroll
    for (int nt = 0; nt < 2; ++nt) {
      const int col = w * 32 + nt * 16 + (lane & 15);
#pragma unroll
      for (int reg = 0; reg < 4; ++reg) {
        const int row = Mt * 16 + (lane >> 4) * 4 + reg;
        ob[row * 132 + col] = acc[Mt][nt][reg];
      }
    }
  __syncthreads();
  {
    const int r = tid >> 2;
    const int gr = row0 + r;
    if (gr < nrows) {
      const float sc = RS / norm[gr];
      const int cb = (tid & 3) * 32;
#pragma unroll
      for (int j = 0; j < 32; j += 4) {
        float4 v = *(const float4*)&ob[r * 132 + cb + j];
        const float4 b = *(const float4*)&bias[cb + j];
        h16x4 pk;
        pk[0] = (_Float16)(fmaxf(v.x + b.x, 0.f) * sc);
        pk[1] = (_Float16)(fmaxf(v.y + b.y, 0.f) * sc);
        pk[2] = (_Float16)(fmaxf(v.z + b.z, 0.f) * sc);
        pk[3] = (_Float16)(fmaxf(v.w + b.w, 0.f) * sc);
        *(h16x4*)(h2h + (size_t)gr * 128 + cb + j) = pk;
      }
    }
  }
}

// ---------------- MP layers 1/2 GEMM: A pre-split in global frag layout ----
// Reads Ahi/Alo directly (lane-contiguous 16B, coalesced; L2-hot for waves 1-3).
// MFMA order identical to mp_gemm_mfma -> bit-identical results.
__global__ __launch_bounds__(256) void mp_gemm_pre(
    const unsigned short* __restrict__ Ahi, const unsigned short* __restrict__ Alo,
    const unsigned short* __restrict__ Wh, const unsigned short* __restrict__ Wl,
    const float* __restrict__ bias, const float* __restrict__ norm,
    _Float16* __restrict__ h2h, int nrows)
{
  __shared__ __attribute__((aligned(16))) float ob[64][132];
  const int tid  = threadIdx.x;
  const int row0 = blockIdx.x * 64;
  const int w = tid >> 6, lane = tid & 63;
  const size_t tb = (size_t)blockIdx.x * 16384;   // ushort elems per tile
  f32x4 acc[4][2] = {};

#pragma unroll
  for (int ks = 0; ks < 4; ++ks) {
    short8 bh[2], bl[2];
#pragma unroll
    for (int nt = 0; nt < 2; ++nt) {
      const int t = w * 2 + nt;
      const size_t ofs = (size_t)(t * 4 + ks) * 512 + lane * 8;
      bh[nt] = *(const short8*)(Wh + ofs);
      bl[nt] = *(const short8*)(Wl + ofs);
    }
#pragma unroll
    for (int Mt = 0; Mt < 4; ++Mt) {
      const size_t fe = tb + (size_t)((Mt * 4 + ks) * 64 + lane) * 8;
      short8 hh = *(const short8*)(Ahi + fe);
      short8 hl = *(const short8*)(Alo + fe);
#pragma unroll
      for (int nt = 0; nt < 2; ++nt) {
        f32x4 a = acc[Mt][nt];
        a = __builtin_amdgcn_mfma_f32_16x16x32_bf16(hh, bh[nt], a, 0, 0, 0);
        a = __builtin_amdgcn_mfma_f32_16x16x32_bf16(hh, bl[nt], a, 0, 0, 0);
        a = __builtin_amdgcn_mfma_f32_16x16x32_bf16(hl, bh[nt], a, 0, 0, 0);
        acc[Mt][nt] = a;
      }
    }
  }

#pragma unroll
  for (int Mt = 0; Mt < 4; ++Mt)
#pragma unroll
    for (int nt = 0; nt < 2; ++nt) {
      const int col = w * 32 + nt * 16 + (lane & 15);
#pragma unroll
      for (int reg = 0; reg < 4; ++reg) {
        const int row = Mt * 16 + (lane >> 4) * 4 + reg;
        ob[row][col] = acc[Mt][nt][reg];
      }
    }
  __syncthreads();
  {
    const int r = tid >> 2;
    const int gr = row0 + r;
    if (gr < nrows) {
      const float sc = RS / norm[gr];
      const int cb = (tid & 3) * 32;
#pragma unroll
      for (int j = 0; j < 32; j += 4) {
        float4 v = *(const float4*)&ob[r][cb + j];
        const float4 b = *(const float4*)&bias[cb + j];
        h16x4 pk;
        pk[0] = (_Float16)(fmaxf(v.x + b.x, 0.f) * sc);
        pk[1] = (_Float16)(fmaxf(v.y + b.y, 0.f) * sc);
        pk[2] = (_Float16)(fmaxf(v.z + b.z, 0.f) * sc);
        pk[3] = (_Float16)(fmaxf(v.w + b.w, 0.f) * sc);
        *(h16x4*)(h2h + (size_t)gr * 128 + cb + j) = pk;
      }
    }
  }
}

// out_hi/lo[t] = split( (1+eps)*h2[t] + sum_{e in CSR[t]} h2[src[e]] )
// fp16 gather + fp32 acc (verified R9); epilogue stores bf16 hi/lo in
// tile-frag-linear layout: lane (c=lane&15) owns cols [c*8,c*8+8) = one 16B
// frag chunk (ks=c>>2, kg=c&3). Same 32B/lane written as the old fp32 path.
__global__ __launch_bounds__(256) void agg_kernel(
    const _Float16* __restrict__ h2h, const int* __restrict__ rowptr,
    const int* __restrict__ ssrc, unsigned short* __restrict__ Hhi,
    unsigned short* __restrict__ Hlo, int N)
{
  const int wv   = (blockIdx.x * 256 + threadIdx.x) >> 6;
  const int lane = threadIdx.x & 63;
  const int node = wv * 4 + (lane >> 4);
  const int c    = lane & 15;
  const int col  = c * 8;
  if (node >= N) return;
  float acc[8];
  {
    const h16x8 sv = *(const h16x8*)(h2h + (size_t)node * 128 + col);
#pragma unroll
    for (int j = 0; j < 8; ++j) acc[j] = ONE_EPS * (float)sv[j];
  }
  const int beg = rowptr[node], end = rowptr[node + 1];
  int i = beg;
  for (; i + 1 < end; i += 2) {
    const int s0 = ssrc[i], s1 = ssrc[i + 1];
    const h16x8 v0 = *(const h16x8*)(h2h + (size_t)s0 * 128 + col);
    const h16x8 v1 = *(const h16x8*)(h2h + (size_t)s1 * 128 + col);
#pragma unroll
    for (int j = 0; j < 8; ++j) acc[j] += (float)v0[j] + (float)v1[j];
  }
  if (i < end) {
    const int s = ssrc[i];
    const h16x8 v = *(const h16x8*)(h2h + (size_t)s * 128 + col);
#pragma unroll
    for (int j = 0; j < 8; ++j) acc[j] += (float)v[j];
  }
  short8 h8, l8;
#pragma unroll
  for (int j = 0; j < 8; ++j) {
    const unsigned short hi = bf16rne(acc[j]);
    h8[j] = (short)hi;
    l8[j] = (short)bf16rne(acc[j] - bf16tof(hi));
  }
  const int T = node >> 6, r = node & 63;
  const int Mt = r >> 4, r16 = r & 15, ks = c >> 2, kg = c & 3;
  const size_t fe = (size_t)T * 16384 + (size_t)((Mt * 4 + ks) * 64 + kg * 16 + r16) * 8;
  *(short8*)(Hhi + fe) = h8;
  *(short8*)(Hlo + fe) = l8;
}

// ---------------- fused output MLP, split-bf16 MFMA (verified R4) ----------
// R14: A staging is a flat memcpy of the pre-split tile (no conversion).
__global__ __launch_bounds__(256) void fused_out_mfma(
    const unsigned short* __restrict__ Ahi, const unsigned short* __restrict__ Alo,
    const unsigned short* __restrict__ FW0h, const unsigned short* __restrict__ FW0l,
    const unsigned short* __restrict__ PW0h, const unsigned short* __restrict__ PW0l,
    const unsigned short* __restrict__ WC1h, const unsigned short* __restrict__ WC1l,
    const unsigned short* __restrict__ WC2h, const unsigned short* __restrict__ WC2l,
    const float* __restrict__ bsum, const float* __restrict__ bc,
    float* __restrict__ out, int nrows)
{
  __shared__ __attribute__((aligned(16))) char smem[65536];
  const int tid  = threadIdx.x;
  const int row0 = blockIdx.x * 64;

  {
    const size_t tb = (size_t)blockIdx.x * 16384;
#pragma unroll
    for (int it = 0; it < 4; ++it) {
      const int i = it * 256 + tid;        // 1024 chunks of 16B
      *(short8*)(smem + i * 16)         = *(const short8*)(Ahi + tb + (size_t)i * 8);
      *(short8*)(smem + 16384 + i * 16) = *(const short8*)(Alo + tb + (size_t)i * 8);
    }
  }
  __syncthreads();

  const int w = tid >> 6, lane = tid & 63;
  union U8 { short8 s; unsigned int u[4]; };

  f32x4 oacc[4][4] = {};

  for (int sc = 0; sc < 4; ++sc) {
    f32x4 zacc[4][2] = {};
#pragma unroll
    for (int ks = 0; ks < 4; ++ks) {
      short8 w0h[2], w0l[2], p0h[2], p0l[2];
#pragma unroll
      for (int nt = 0; nt < 2; ++nt) {
        const int t = w * 8 + sc * 2 + nt;
        const size_t ofs = (size_t)(t * 4 + ks) * 512 + lane * 8;
        w0h[nt] = *(const short8*)(FW0h + ofs);
        w0l[nt] = *(const short8*)(FW0l + ofs);
        p0h[nt] = *(const short8*)(PW0h + ofs);
        p0l[nt] = *(const short8*)(PW0l + ofs);
      }
#pragma unroll
      for (int Mt = 0; Mt < 4; ++Mt) {
        const int fb = ((Mt * 4 + ks) * 64 + lane) * 16;
        U8 hh, hl, rh, rl;
        hh.s = *(const short8*)(smem + fb);
        hl.s = *(const short8*)(smem + 16384 + fb);
#pragma unroll
        for (int u = 0; u < 4; ++u) {
          unsigned int msk = ((hh.u[u] & 0x80008000u) >> 15) * 0xFFFFu;
          rh.u[u] = hh.u[u] & ~msk;
          rl.u[u] = hl.u[u] & ~msk;
        }
#pragma unroll
        for (int nt = 0; nt < 2; ++nt) {
          f32x4 a = zacc[Mt][nt];
          a = __builtin_amdgcn_mfma_f32_16x16x32_bf16(rh.s, w0h[nt], a, 0, 0, 0);
          a = __builtin_amdgcn_mfma_f32_16x16x32_bf16(rh.s, w0l[nt], a, 0, 0, 0);
          a = __builtin_amdgcn_mfma_f32_16x16x32_bf16(rl.s, w0h[nt], a, 0, 0, 0);
          a = __builtin_amdgcn_mfma_f32_16x16x32_bf16(hh.s, p0h[nt], a, 0, 0, 0);
          a = __builtin_amdgcn_mfma_f32_16x16x32_bf16(hh.s, p0l[nt], a, 0, 0, 0);
          a = __builtin_amdgcn_mfma_f32_16x16x32_bf16(hl.s, p0h[nt], a, 0, 0, 0);
          zacc[Mt][nt] = a;
        }
      }
    }
    const float bs0 = bsum[w * 128 + sc * 32 + (lane & 15)];
    const float bs1 = bsum[w * 128 + sc * 32 + 16 + (lane & 15)];
#pragma unroll
    for (int Mt = 0; Mt < 4; ++Mt) {
#pragma unroll
      for (int nt = 0; nt < 2; ++nt) {
        const float bs = nt ? bs1 : bs0;
        const int kg = nt * 2 + ((lane >> 3) & 1);
        const int eb = (lane & 7) * 2;
#pragma unroll
        for (int reg = 0; reg < 4; ++reg) {
          const float zv = fmaxf(zacc[Mt][nt][reg] + bs, 0.f);
          const unsigned short zhi = bf16rne(zv);
          const unsigned short zlo = bf16rne(zv - bf16tof(zhi));
          const int r16 = (lane >> 4) * 4 + reg;
          const int fb = ((w * 4 + Mt) * 64 + kg * 16 + r16) * 16 + eb;
          *(unsigned short*)(smem + 32768 + fb) = zhi;
          *(unsigned short*)(smem + 49152 + fb) = zlo;
        }
      }
    }
    asm volatile("s_waitcnt lgkmcnt(0)" ::: "memory");
    const int s2 = w * 4 + sc;
    short8 c1h[4], c1l[4];
#pragma unroll
    for (int t2 = 0; t2 < 4; ++t2) {
      const size_t ofs = (size_t)(t2 * 16 + s2) * 512 + lane * 8;
      c1h[t2] = *(const short8*)(WC1h + ofs);
      c1l[t2] = *(const short8*)(WC1l + ofs);
    }
#pragma unroll
    for (int Mt = 0; Mt < 4; ++Mt) {
      const int fb = ((w * 4 + Mt) * 64 + lane) * 16;
      short8 zh8 = *(const short8*)(smem + 32768 + fb);
      short8 zl8 = *(const short8*)(smem + 49152 + fb);
#pragma unroll
      for (int t2 = 0; t2 < 4; ++t2) {
        f32x4 a = oacc[Mt][t2];
        a = __builtin_amdgcn_mfma_f32_16x16x32_bf16(zh8, c1h[t2], a, 0, 0, 0);
        a = __builtin_amdgcn_mfma_f32_16x16x32_bf16(zh8, c1l[t2], a, 0, 0, 0);
        a = __builtin_amdgcn_mfma_f32_16x16x32_bf16(zl8, c1h[t2], a, 0, 0, 0);
        oacc[Mt][t2] = a;
      }
    }
  }

  {
    short8 c2h[4], c2l[4];
#pragma unroll
    for (int t = 0; t < 4; ++t) {
      const size_t ofs = (size_t)(t * 4 + w) * 512 + lane * 8;
      c2h[t] = *(const short8*)(WC2h + ofs);
      c2l[t] = *(const short8*)(WC2l + ofs);
    }
#pragma unroll
    for (int Mt = 0; Mt < 4; ++Mt) {
      const int fb = ((Mt * 4 + w) * 64 + lane) * 16;
      short8 hh = *(const short8*)(smem + fb);
      short8 hl = *(const short8*)(smem + 16384 + fb);
#pragma unroll
      for (int t = 0; t < 4; ++t) {
        f32x4 a = oacc[Mt][t];
        a = __builtin_amdgcn_mfma_f32_16x16x32_bf16(hh, c2h[t], a, 0, 0, 0);
        a = __builtin_amdgcn_mfma_f32_16x16x32_bf16(hh, c2l[t], a, 0, 0, 0);
        a = __builtin_amdgcn_mfma_f32_16x16x32_bf16(hl, c2h[t], a, 0, 0, 0);
        oacc[Mt][t] = a;
      }
    }
  }

  __syncthreads();
  float* red = (float*)smem;
#pragma unroll
  for (int Mt = 0; Mt < 4; ++Mt)
#pragma unroll
    for (int Nt = 0; Nt < 4; ++Nt)
#pragma unroll
      for (int reg = 0; reg < 4; ++reg) {
        const int row = Mt * 16 + (lane >> 4) * 4 + reg;
        const int col = Nt * 16 + (lane & 15);
        red[(w * 64 + row) * 64 + col] = oacc[Mt][Nt][reg];
      }
  __syncthreads();
  {
    const int c4 = (tid & 15) * 4;
    const int rb = tid >> 4;
    const float4 bcv = *(const float4*)(bc + c4);
#pragma unroll
    for (int rr = 0; rr < 4; ++rr) {
      const int r = rr * 16 + rb;
      const int gr = row0 + r;
      if (gr < nrows) {
        float4 s = bcv;
#pragma unroll
        for (int wv = 0; wv < 4; ++wv) {
          const float4 p = *(const float4*)&red[(wv * 64 + r) * 64 + c4];
          s.x += p.x; s.y += p.y; s.z += p.z; s.w += p.w;
        }
        *(float4*)(out + (size_t)gr * 64 + c4) = s;
      }
    }
  }
}

// ---------------------------------------------------------------------------
extern "C" void kernel_launch(void* const* d_in, const int* in_sizes, int n_in,
                              void* d_out, int out_size, void* d_ws, size_t ws_size,
                              hipStream_t stream) {
  const float* x    = (const float*)d_in[0];
  const int*   ei   = (const int*)d_in[1];   // [2][E] int32
  const float* mpW0 = (const float*)d_in[2];
  const float* mpb0 = (const float*)d_in[3];
  const float* mpW1 = (const float*)d_in[4];
  const float* mpb1 = (const float*)d_in[5];
  const float* mpW2 = (const float*)d_in[6];
  const float* mpb2 = (const float*)d_in[7];
  const float* fcW0 = (const float*)d_in[8];
  const float* fcb0 = (const float*)d_in[9];
  const float* fcW1 = (const float*)d_in[10];
  const float* fcb1 = (const float*)d_in[11];
  const float* pW0  = (const float*)d_in[12];
  const float* pb0  = (const float*)d_in[13];
  const float* pW1  = (const float*)d_in[14];
  const float* pb1  = (const float*)d_in[15];
  const float* outW = (const float*)d_in[16];
  const float* outb = (const float*)d_in[17];

  const int N = in_sizes[0] / 128;
  const int E = in_sizes[1] / 2;
  const int NB    = (N + 127) / 128;         // coarse buckets (<=1024)
  const int NBLK  = (E + CH - 1) / CH;       // P1/P3 blocks
  const int tiles = (N + 63) / 64;

  char* ws = (char*)d_ws;
  size_t off = 0;
  auto alloc = [&](size_t bytes) -> char* {
    char* p = ws + off;
    off += (bytes + 255) & ~(size_t)255;
    return p;
  };
  float* norm   = (float*)alloc((size_t)N * 4);
  int*   rowptr = (int*)alloc((size_t)(N + 1) * 4);
  int*   bcnt_t = (int*)alloc((size_t)NB * NBLK * 4);
  int*   bcnt_s = (int*)alloc((size_t)NB * NBLK * 4);
  int*   ofs_t  = (int*)alloc((size_t)NB * NBLK * 4);
  int*   ofs_s  = (int*)alloc((size_t)NB * NBLK * 4);
  int*   tot_t  = (int*)alloc((size_t)NB * 4);
  int*   tot_s  = (int*)alloc((size_t)NB * 4);
  int*   barr_t = (int*)alloc((size_t)(NB + 1) * 4);
  int*   barr_s = (int*)alloc((size_t)(NB + 1) * 4);
  int*   ssrc   = (int*)alloc((size_t)E * 4);
  int*   ssbin  = (int*)alloc((size_t)E * 4);
  unsigned long long* sorted = (unsigned long long*)alloc((size_t)E * 8);
  _Float16* h2h = (_Float16*)alloc((size_t)N * 128 * 2);
  unsigned short* Hhi = (unsigned short*)alloc((size_t)tiles * 16384 * 2);
  unsigned short* Hlo = (unsigned short*)alloc((size_t)tiles * 16384 * 2);
  float* Wc1    = (float*)alloc(512 * 64 * 4);
  float* Wc2    = (float*)alloc(128 * 64 * 4);
  float* bc     = (float*)alloc(64 * 4);
  unsigned short* FW0h = (unsigned short*)alloc(65536 * 2);
  unsigned short* FW0l = (unsigned short*)alloc(65536 * 2);
  unsigned short* PW0h = (unsigned short*)alloc(65536 * 2);
  unsigned short* PW0l = (unsigned short*)alloc(65536 * 2);
  unsigned short* WC1h = (unsigned short*)alloc(32768 * 2);
  unsigned short* WC1l = (unsigned short*)alloc(32768 * 2);
  unsigned short* WC2h = (unsigned short*)alloc(8192 * 2);
  unsigned short* WC2l = (unsigned short*)alloc(8192 * 2);
  float* bsum   = (float*)alloc(512 * 4);
  unsigned short* M0h = (unsigned short*)alloc(16384 * 2);
  unsigned short* M0l = (unsigned short*)alloc(16384 * 2);
  unsigned short* M1h = (unsigned short*)alloc(16384 * 2);
  unsigned short* M1l = (unsigned short*)alloc(16384 * 2);
  unsigned short* M2h = (unsigned short*)alloc(16384 * 2);
  unsigned short* M2l = (unsigned short*)alloc(16384 * 2);
  // total ~= 125 MiB (hbuf 51MB removed, Hhi/Hlo 51MB added, ofs/bcnt grow)

  const int scblocks = (NB + 3) / 4;

  p1_kernel<<<NBLK, 256, 0, stream>>>(ei, E, NB, NBLK, bcnt_t, bcnt_s);
  scan_tot<<<scblocks, 256, 0, stream>>>(bcnt_t, tot_t, NBLK, NB);
  scan_tot<<<scblocks, 256, 0, stream>>>(bcnt_s, tot_s, NBLK, NB);
  scan_base<<<1, 1024, 0, stream>>>(tot_t, barr_t, NB, E, rowptr, N);
  scan_base<<<1, 1024, 0, stream>>>(tot_s, barr_s, NB, E, nullptr, 0);
  scan_ofs<<<scblocks, 256, 0, stream>>>(bcnt_t, barr_t, ofs_t, NBLK, NB);
  scan_ofs<<<scblocks, 256, 0, stream>>>(bcnt_s, barr_s, ofs_s, NBLK, NB);
  p3_kernel<<<NBLK, 256, 0, stream>>>(ei, E, NB, NBLK, ofs_t, ofs_s, sorted, ssbin);
  p4_kernel<<<NB, 256, 0, stream>>>(sorted, barr_t, rowptr, ssrc, N);
  p4b_kernel<<<NB, 256, 0, stream>>>(ssbin, barr_s, norm, N);
  combine_kernel<<<(512 * 64 + 128 * 64 + 64 + 255) / 256, 256, 0, stream>>>(
      fcW1, fcb1, pW1, pb1, outW, outb, Wc1, Wc2, bc);
  convw_kernel<<<(65536 + 32768 + 8192 + 512 + 255) / 256, 256, 0, stream>>>(
      fcW0, pW0, Wc1, Wc2, fcb0, pb0,
      FW0h, FW0l, PW0h, PW0l, WC1h, WC1l, WC2h, WC2l, bsum);
  convmp_kernel<<<(3 * 16384 + 255) / 256, 256, 0, stream>>>(
      mpW0, mpW1, mpW2, M0h, M0l, M1h, M1l, M2h, M2l);

  const int gx = tiles;
  const int ablocks = (N + 15) / 16;   // 4 waves/block, 4 nodes/wave

  mp_gemm_mfma<<<gx, 256, 0, stream>>>(x, M0h, M0l, mpb0, norm, h2h, N);
  agg_kernel<<<ablocks, 256, 0, stream>>>(h2h, rowptr, ssrc, Hhi, Hlo, N);
  mp_gemm_pre<<<gx, 256, 0, stream>>>(Hhi, Hlo, M1h, M1l, mpb1, norm, h2h, N);
  agg_kernel<<<ablocks, 256, 0, stream>>>(h2h, rowptr, ssrc, Hhi, Hlo, N);
  mp_gemm_pre<<<gx, 256, 0, stream>>>(Hhi, Hlo, M2h, M2l, mpb2, norm, h2h, N);
  agg_kernel<<<ablocks, 256, 0, stream>>>(h2h, rowptr, ssrc, Hhi, Hlo, N);

  fused_out_mfma<<<gx, 256, 0, stream>>>(
      Hhi, Hlo, FW0h, FW0l, PW0h, PW0l, WC1h, WC1l, WC2h, WC2l, bsum, bc,
      (float*)d_out, N);
}

// Round 15
// 532.053 us; speedup vs baseline: 1.0425x; 1.0344x over previous
//
#include <hip/hip_runtime.h>

// DecoupleModel: 3x GIN MP layers (split-bf16 MFMA) + CSR-gather aggregation
// + fused output MLP (split-bf16 MFMA).
// R15 = R14 with dispatch merging only (zero math change):
//   scan_tot x2 -> 1, scan_base x2 -> 1, scan_ofs x2 -> 1, p4b into p4,
//   convmp into convw. 20 -> 15 dispatches.

typedef __attribute__((ext_vector_type(8))) short short8;
typedef __attribute__((ext_vector_type(4))) float f32x4;
typedef __attribute__((ext_vector_type(8))) _Float16 h16x8;
typedef __attribute__((ext_vector_type(4))) _Float16 h16x4;

constexpr float SQRT2   = 1.41421356237309515f;
constexpr float ONE_EPS = 1.0f + SQRT2;          // (1 + eps)
constexpr float RS      = 0.08838834764831845f;  // 1/sqrt(128)
constexpr int   CH      = 4096;                  // edges per P1/P3 block

__device__ inline unsigned short bf16rne(float f) {
  unsigned int u = __float_as_uint(f);
  return (unsigned short)((u + 0x7FFFu + ((u >> 16) & 1u)) >> 16);
}
__device__ inline float bf16tof(unsigned short h) {
  return __uint_as_float(((unsigned int)h) << 16);
}

// ---------------- graph preprocessing --------------------------------------
__global__ __launch_bounds__(256) void p1_kernel(
    const int* __restrict__ ei, int E, int NB, int NBLK,
    int* __restrict__ bcnt_t, int* __restrict__ bcnt_s) {
  __shared__ int cb[1024], cb2[1024];
  for (int i = threadIdx.x; i < 1024; i += 256) { cb[i] = 0; cb2[i] = 0; }
  __syncthreads();
  const int base = blockIdx.x * CH;
#pragma unroll 4
  for (int it = 0; it < CH / 256; ++it) {
    const int e = base + it * 256 + threadIdx.x;
    if (e < E) {
      atomicAdd(&cb[ei[e] >> 7], 1);
      atomicAdd(&cb2[ei[E + e] >> 7], 1);
    }
  }
  __syncthreads();
  for (int i = threadIdx.x; i < NB; i += 256) {
    bcnt_t[(size_t)i * NBLK + blockIdx.x] = cb[i];
    bcnt_s[(size_t)i * NBLK + blockIdx.x] = cb2[i];
  }
}

// merged: first half of grid -> bcnt_t/tot_t ; second half -> bcnt_s/tot_s
__global__ __launch_bounds__(256) void scan_tot2(
    const int* __restrict__ bcnt_t, const int* __restrict__ bcnt_s,
    int* __restrict__ tot_t, int* __restrict__ tot_s,
    int NBLK, int NB, int scb) {
  const int half = blockIdx.x / scb;
  const int bi   = blockIdx.x % scb;
  const int* bcnt = half ? bcnt_s : bcnt_t;
  int* tot        = half ? tot_s : tot_t;
  const int wid = bi * 4 + (threadIdx.x >> 6);
  const int lane = threadIdx.x & 63;
  if (wid >= NB) return;
  int s = 0;
  for (int b = lane; b < NBLK; b += 64) s += bcnt[(size_t)wid * NBLK + b];
  for (int o = 32; o > 0; o >>= 1) s += __shfl_down(s, o);
  if (lane == 0) tot[wid] = s;
}

// merged: block 0 -> barr_t (+rowptr[N]) ; block 1 -> barr_s
__global__ __launch_bounds__(1024) void scan_base2(
    const int* __restrict__ tot_t, const int* __restrict__ tot_s,
    int* __restrict__ barr_t, int* __restrict__ barr_s,
    int NB, int E, int* __restrict__ rowptr, int N) {
  __shared__ int sh[1024];
  const int* tot = blockIdx.x ? tot_s : tot_t;
  int* barr      = blockIdx.x ? barr_s : barr_t;
  const int t = threadIdx.x;
  const int v = (t < NB) ? tot[t] : 0;
  sh[t] = v;
  __syncthreads();
  for (int o = 1; o < 1024; o <<= 1) {
    int u = (t >= o) ? sh[t - o] : 0;
    __syncthreads();
    sh[t] += u;
    __syncthreads();
  }
  if (t < NB) barr[t] = sh[t] - v;
  if (t == 0) { barr[NB] = E; if (blockIdx.x == 0) rowptr[N] = E; }
}

// merged: first half -> ofs_t ; second half -> ofs_s
__global__ __launch_bounds__(256) void scan_ofs2(
    const int* __restrict__ bcnt_t, const int* __restrict__ bcnt_s,
    const int* __restrict__ barr_t, const int* __restrict__ barr_s,
    int* __restrict__ ofs_t, int* __restrict__ ofs_s,
    int NBLK, int NB, int scb) {
  const int half = blockIdx.x / scb;
  const int bi   = blockIdx.x % scb;
  const int* bcnt = half ? bcnt_s : bcnt_t;
  const int* barr = half ? barr_s : barr_t;
  int* ofs        = half ? ofs_s : ofs_t;
  const int wid = bi * 4 + (threadIdx.x >> 6);
  const int lane = threadIdx.x & 63;
  if (wid >= NB) return;
  int run = barr[wid];
  for (int c0 = 0; c0 < NBLK; c0 += 64) {
    const int idx = c0 + lane;
    const int v = (idx < NBLK) ? bcnt[(size_t)wid * NBLK + idx] : 0;
    int incl = v;
#pragma unroll
    for (int o = 1; o < 64; o <<= 1) {
      int u = __shfl_up(incl, o);
      if (lane >= o) incl += u;
    }
    if (idx < NBLK) ofs[(size_t)wid * NBLK + idx] = run + incl - v;
    run += __shfl(incl, 63);
  }
}

__global__ __launch_bounds__(256) void p3_kernel(
    const int* __restrict__ ei, int E, int NB, int NBLK,
    const int* __restrict__ ofs_t, const int* __restrict__ ofs_s,
    unsigned long long* __restrict__ sorted, int* __restrict__ ssbin) {
  __shared__ int cur[1024], cur2[1024];
  for (int i = threadIdx.x; i < NB; i += 256) {
    cur[i]  = ofs_t[(size_t)i * NBLK + blockIdx.x];
    cur2[i] = ofs_s[(size_t)i * NBLK + blockIdx.x];
  }
  __syncthreads();
  const int base = blockIdx.x * CH;
  for (int it = 0; it < CH / 256; ++it) {
    const int e = base + it * 256 + threadIdx.x;
    if (e < E) {
      const int tgt = ei[e], src = ei[E + e];
      const int pos = atomicAdd(&cur[tgt >> 7], 1);
      sorted[pos] = ((unsigned long long)(unsigned)tgt << 32) | (unsigned)src;
      const int pos2 = atomicAdd(&cur2[src >> 7], 1);
      ssbin[pos2] = src;
    }
  }
}

// merged p4 + p4b: blocks [0,NB) build rowptr/ssrc; blocks [NB,2NB) build norm
__global__ __launch_bounds__(256) void p4m_kernel(
    const unsigned long long* __restrict__ sorted, const int* __restrict__ barr_t,
    int* __restrict__ rowptr, int* __restrict__ ssrc,
    const int* __restrict__ ssbin, const int* __restrict__ barr_s,
    float* __restrict__ norm, int N, int NB) {
  __shared__ int fcnt[128], fcur[128], sh[128];
  const int t = threadIdx.x;
  if (blockIdx.x < NB) {
    const int B = blockIdx.x;
    const int lo = barr_t[B], hi = barr_t[B + 1];
    if (t < 128) fcnt[t] = 0;
    __syncthreads();
    for (int i = lo + t; i < hi; i += 256)
      atomicAdd(&fcnt[(int)(sorted[i] >> 32) & 127], 1);
    __syncthreads();
    if (t < 128) sh[t] = fcnt[t];
    __syncthreads();
    for (int o = 1; o < 128; o <<= 1) {
      int v = 0;
      if (t < 128 && t >= o) v = sh[t - o];
      __syncthreads();
      if (t < 128) sh[t] += v;
      __syncthreads();
    }
    if (t < 128) {
      const int base = lo + sh[t] - fcnt[t];   // exclusive
      fcur[t] = base;
      const int node = B * 128 + t;
      if (node < N) rowptr[node] = base;
    }
    __syncthreads();
    for (int i = lo + t; i < hi; i += 256) {
      const unsigned long long p = sorted[i];
      const int pos = atomicAdd(&fcur[(int)(p >> 32) & 127], 1);
      ssrc[pos] = (int)(unsigned)(p & 0xffffffffu);
    }
  } else {
    const int B = blockIdx.x - NB;
    const int lo = barr_s[B], hi = barr_s[B + 1];
    if (t < 128) fcnt[t] = 0;
    __syncthreads();
    for (int i = lo + t; i < hi; i += 256)
      atomicAdd(&fcnt[ssbin[i] & 127], 1);
    __syncthreads();
    if (t < 128) {
      const int node = B * 128 + t;
      if (node < N) norm[node] = ONE_EPS + (float)fcnt[t];
    }
  }
}

// ---------------- weight folding -------------------------------------------
__global__ void combine_kernel(const float* __restrict__ fcW1, const float* __restrict__ fcb1,
                               const float* __restrict__ pW1,  const float* __restrict__ pb1,
                               const float* __restrict__ outW, const float* __restrict__ outb,
                               float* __restrict__ Wc1, float* __restrict__ Wc2,
                               float* __restrict__ bc) {
  int gid = blockIdx.x * blockDim.x + threadIdx.x;
  if (gid < 512 * 64) {
    int k = gid >> 6, j = gid & 63;
    float s = 0.f;
    for (int m = 0; m < 512; ++m) s = fmaf(fcW1[k * 512 + m], outW[m * 64 + j], s);
    Wc1[gid] = s;
  } else if (gid < 512 * 64 + 128 * 64) {
    int t = gid - 512 * 64, k = t >> 6, j = t & 63;
    float s = 0.f;
    for (int m = 0; m < 512; ++m) s = fmaf(pW1[k * 512 + m], outW[m * 64 + j], s);
    Wc2[t] = s;
  } else if (gid < 512 * 64 + 128 * 64 + 64) {
    int j = gid - (512 * 64 + 128 * 64);
    float s = outb[j];
    for (int m = 0; m < 512; ++m) s = fmaf(fcb1[m] + pb1[m], outW[m * 64 + j], s);
    bc[j] = s;
  }
}

// convw + convmp merged (convmp range appended after bsum)
__global__ void convw_kernel(const float* __restrict__ fcW0, const float* __restrict__ pW0,
                             const float* __restrict__ Wc1,  const float* __restrict__ Wc2,
                             const float* __restrict__ fcb0, const float* __restrict__ pb0,
                             const float* __restrict__ W0, const float* __restrict__ W1,
                             const float* __restrict__ W2,
                             unsigned short* __restrict__ FW0h, unsigned short* __restrict__ FW0l,
                             unsigned short* __restrict__ PW0h, unsigned short* __restrict__ PW0l,
                             unsigned short* __restrict__ WC1h, unsigned short* __restrict__ WC1l,
                             unsigned short* __restrict__ WC2h, unsigned short* __restrict__ WC2l,
                             float* __restrict__ bsum,
                             unsigned short* __restrict__ M0h, unsigned short* __restrict__ M0l,
                             unsigned short* __restrict__ M1h, unsigned short* __restrict__ M1l,
                             unsigned short* __restrict__ M2h, unsigned short* __restrict__ M2l) {
  int gid = blockIdx.x * blockDim.x + threadIdx.x;
  if (gid < 65536) {
    int e = gid & 7, c = (gid >> 3) & 15, kg = (gid >> 7) & 3, s = (gid >> 9) & 3, t = gid >> 11;
    int k = s * 32 + kg * 8 + e, n = t * 16 + c;
    float f = fcW0[k * 512 + n];
    unsigned short h = bf16rne(f);
    FW0h[gid] = h; FW0l[gid] = bf16rne(f - bf16tof(h));
    f = pW0[k * 512 + n];
    h = bf16rne(f);
    PW0h[gid] = h; PW0l[gid] = bf16rne(f - bf16tof(h));
  } else if (gid < 65536 + 32768) {
    int g = gid - 65536;
    int e = g & 7, c = (g >> 3) & 15, kg = (g >> 7) & 3, s = (g >> 9) & 15, t = g >> 13;
    int k = s * 32 + kg * 8 + e, n = t * 16 + c;
    float f = Wc1[k * 64 + n];
    unsigned short h = bf16rne(f);
    WC1h[g] = h; WC1l[g] = bf16rne(f - bf16tof(h));
  } else if (gid < 65536 + 32768 + 8192) {
    int g = gid - 98304;
    int e = g & 7, c = (g >> 3) & 15, kg = (g >> 7) & 3, s = (g >> 9) & 3, t = (g >> 11) & 3;
    int k = s * 32 + kg * 8 + e, n = t * 16 + c;
    float f = Wc2[k * 64 + n];
    unsigned short h = bf16rne(f);
    WC2h[g] = h; WC2l[g] = bf16rne(f - bf16tof(h));
  } else if (gid < 106496 + 512) {
    int j = gid - 106496;
    bsum[j] = fcb0[j] + pb0[j];
  } else if (gid < 107008 + 3 * 16384) {
    int gg = gid - 107008;
    const int m = gg >> 14, g = gg & 16383;
    int e = g & 7, c = (g >> 3) & 15, kg = (g >> 7) & 3, s = (g >> 9) & 3, t = g >> 11;
    int k = s * 32 + kg * 8 + e, n = t * 16 + c;
    const float* W = (m == 0) ? W0 : (m == 1) ? W1 : W2;
    unsigned short* Mh = (m == 0) ? M0h : (m == 1) ? M1h : M2h;
    unsigned short* Ml = (m == 0) ? M0l : (m == 1) ? M1l : M2l;
    float f = W[k * 128 + n];
    unsigned short h = bf16rne(f);
    Mh[g] = h; Ml[g] = bf16rne(f - bf16tof(h));
  }
}

// ---------------- MP layer 0 GEMM (fp32 input x, verified R5/R9) -----------
__global__ __launch_bounds__(256) void mp_gemm_mfma(
    const float* __restrict__ A,
    const unsigned short* __restrict__ Wh, const unsigned short* __restrict__ Wl,
    const float* __restrict__ bias, const float* __restrict__ norm,
    _Float16* __restrict__ h2h, int nrows)
{
  __shared__ __attribute__((aligned(16))) char smem[33792];
  const int tid  = threadIdx.x;
  const int row0 = blockIdx.x * 64;

  {
    const int m = tid >> 2, q = tid & 3;
    const int gr = row0 + m;
    const int Mt = m >> 4, r16 = m & 15;
#pragma unroll
    for (int it = 0; it < 8; ++it) {
      const int k = it * 16 + q * 4;
      float4 v = make_float4(0.f, 0.f, 0.f, 0.f);
      if (gr < nrows) v = *(const float4*)(A + (size_t)gr * 128 + k);
      const unsigned short h0 = bf16rne(v.x), h1 = bf16rne(v.y);
      const unsigned short h2v = bf16rne(v.z), h3 = bf16rne(v.w);
      const unsigned short l0 = bf16rne(v.x - bf16tof(h0));
      const unsigned short l1 = bf16rne(v.y - bf16tof(h1));
      const unsigned short l2 = bf16rne(v.z - bf16tof(h2v));
      const unsigned short l3 = bf16rne(v.w - bf16tof(h3));
      const int k3 = it * 2 + (q >> 1);
      const int kg = k3 & 3, ks = k3 >> 2;
      const int eb = (q & 1) * 8;
      const int fb = ((Mt * 4 + ks) * 64 + kg * 16 + r16) * 16 + eb;
      *(uint2*)(smem + fb) =
          make_uint2((unsigned)h0 | ((unsigned)h1 << 16), (unsigned)h2v | ((unsigned)h3 << 16));
      *(uint2*)(smem + 16384 + fb) =
          make_uint2((unsigned)l0 | ((unsigned)l1 << 16), (unsigned)l2 | ((unsigned)l3 << 16));
    }
  }
  __syncthreads();

  const int w = tid >> 6, lane = tid & 63;
  f32x4 acc[4][2] = {};

#pragma unroll
  for (int ks = 0; ks < 4; ++ks) {
    short8 bh[2], bl[2];
#pragma unroll
    for (int nt = 0; nt < 2; ++nt) {
      const int t = w * 2 + nt;
      const size_t ofs = (size_t)(t * 4 + ks) * 512 + lane * 8;
      bh[nt] = *(const short8*)(Wh + ofs);
      bl[nt] = *(const short8*)(Wl + ofs);
    }
#pragma unroll
    for (int Mt = 0; Mt < 4; ++Mt) {
      const int fb = ((Mt * 4 + ks) * 64 + lane) * 16;
      short8 hh = *(const short8*)(smem + fb);
      short8 hl = *(const short8*)(smem + 16384 + fb);
#pragma unroll
      for (int nt = 0; nt < 2; ++nt) {
        f32x4 a = acc[Mt][nt];
        a = __builtin_amdgcn_mfma_f32_16x16x32_bf16(hh, bh[nt], a, 0, 0, 0);
        a = __builtin_amdgcn_mfma_f32_16x16x32_bf16(hh, bl[nt], a, 0, 0, 0);
        a = __builtin_amdgcn_mfma_f32_16x16x32_bf16(hl, bh[nt], a, 0, 0, 0);
        acc[Mt][nt] = a;
      }
    }
  }

  __syncthreads();
  float* ob = (float*)smem;
#pragma unroll
  for (int Mt = 0; Mt < 4; ++Mt)
#pragma unroll
    for (int nt = 0; nt < 2; ++nt) {
      const int col = w * 32 + nt * 16 + (lane & 15);
#pragma unroll
      for (int reg = 0; reg < 4; ++reg) {
        const int row = Mt * 16 + (lane >> 4) * 4 + reg;
        ob[row * 132 + col] = acc[Mt][nt][reg];
      }
    }
  __syncthreads();
  {
    const int r = tid >> 2;
    const int gr = row0 + r;
    if (gr < nrows) {
      const float sc = RS / norm[gr];
      const int cb = (tid & 3) * 32;
#pragma unroll
      for (int j = 0; j < 32; j += 4) {
        float4 v = *(const float4*)&ob[r * 132 + cb + j];
        const float4 b = *(const float4*)&bias[cb + j];
        h16x4 pk;
        pk[0] = (_Float16)(fmaxf(v.x + b.x, 0.f) * sc);
        pk[1] = (_Float16)(fmaxf(v.y + b.y, 0.f) * sc);
        pk[2] = (_Float16)(fmaxf(v.z + b.z, 0.f) * sc);
        pk[3] = (_Float16)(fmaxf(v.w + b.w, 0.f) * sc);
        *(h16x4*)(h2h + (size_t)gr * 128 + cb + j) = pk;
      }
    }
  }
}

// ---------------- MP layers 1/2 GEMM: A pre-split in global frag layout ----
__global__ __launch_bounds__(256) void mp_gemm_pre(
    const unsigned short* __restrict__ Ahi, const unsigned short* __restrict__ Alo,
    const unsigned short* __restrict__ Wh, const unsigned short* __restrict__ Wl,
    const float* __restrict__ bias, const float* __restrict__ norm,
    _Float16* __restrict__ h2h, int nrows)
{
  __shared__ __attribute__((aligned(16))) float ob[64][132];
  const int tid  = threadIdx.x;
  const int row0 = blockIdx.x * 64;
  const int w = tid >> 6, lane = tid & 63;
  const size_t tb = (size_t)blockIdx.x * 16384;   // ushort elems per tile
  f32x4 acc[4][2] = {};

#pragma unroll
  for (int ks = 0; ks < 4; ++ks) {
    short8 bh[2], bl[2];
#pragma unroll
    for (int nt = 0; nt < 2; ++nt) {
      const int t = w * 2 + nt;
      const size_t ofs = (size_t)(t * 4 + ks) * 512 + lane * 8;
      bh[nt] = *(const short8*)(Wh + ofs);
      bl[nt] = *(const short8*)(Wl + ofs);
    }
#pragma unroll
    for (int Mt = 0; Mt < 4; ++Mt) {
      const size_t fe = tb + (size_t)((Mt * 4 + ks) * 64 + lane) * 8;
      short8 hh = *(const short8*)(Ahi + fe);
      short8 hl = *(const short8*)(Alo + fe);
#pragma unroll
      for (int nt = 0; nt < 2; ++nt) {
        f32x4 a = acc[Mt][nt];
        a = __builtin_amdgcn_mfma_f32_16x16x32_bf16(hh, bh[nt], a, 0, 0, 0);
        a = __builtin_amdgcn_mfma_f32_16x16x32_bf16(hh, bl[nt], a, 0, 0, 0);
        a = __builtin_amdgcn_mfma_f32_16x16x32_bf16(hl, bh[nt], a, 0, 0, 0);
        acc[Mt][nt] = a;
      }
    }
  }

#pragma unroll
  for (int Mt = 0; Mt < 4; ++Mt)
#pragma unroll
    for (int nt = 0; nt < 2; ++nt) {
      const int col = w * 32 + nt * 16 + (lane & 15);
#pragma unroll
      for (int reg = 0; reg < 4; ++reg) {
        const int row = Mt * 16 + (lane >> 4) * 4 + reg;
        ob[row][col] = acc[Mt][nt][reg];
      }
    }
  __syncthreads();
  {
    const int r = tid >> 2;
    const int gr = row0 + r;
    if (gr < nrows) {
      const float sc = RS / norm[gr];
      const int cb = (tid & 3) * 32;
#pragma unroll
      for (int j = 0; j < 32; j += 4) {
        float4 v = *(const float4*)&ob[r][cb + j];
        const float4 b = *(const float4*)&bias[cb + j];
        h16x4 pk;
        pk[0] = (_Float16)(fmaxf(v.x + b.x, 0.f) * sc);
        pk[1] = (_Float16)(fmaxf(v.y + b.y, 0.f) * sc);
        pk[2] = (_Float16)(fmaxf(v.z + b.z, 0.f) * sc);
        pk[3] = (_Float16)(fmaxf(v.w + b.w, 0.f) * sc);
        *(h16x4*)(h2h + (size_t)gr * 128 + cb + j) = pk;
      }
    }
  }
}

// out_hi/lo[t] = split( (1+eps)*h2[t] + sum_{e in CSR[t]} h2[src[e]] )
__global__ __launch_bounds__(256) void agg_kernel(
    const _Float16* __restrict__ h2h, const int* __restrict__ rowptr,
    const int* __restrict__ ssrc, unsigned short* __restrict__ Hhi,
    unsigned short* __restrict__ Hlo, int N)
{
  const int wv   = (blockIdx.x * 256 + threadIdx.x) >> 6;
  const int lane = threadIdx.x & 63;
  const int node = wv * 4 + (lane >> 4);
  const int c    = lane & 15;
  const int col  = c * 8;
  if (node >= N) return;
  float acc[8];
  {
    const h16x8 sv = *(const h16x8*)(h2h + (size_t)node * 128 + col);
#pragma unroll
    for (int j = 0; j < 8; ++j) acc[j] = ONE_EPS * (float)sv[j];
  }
  const int beg = rowptr[node], end = rowptr[node + 1];
  int i = beg;
  for (; i + 1 < end; i += 2) {
    const int s0 = ssrc[i], s1 = ssrc[i + 1];
    const h16x8 v0 = *(const h16x8*)(h2h + (size_t)s0 * 128 + col);
    const h16x8 v1 = *(const h16x8*)(h2h + (size_t)s1 * 128 + col);
#pragma unroll
    for (int j = 0; j < 8; ++j) acc[j] += (float)v0[j] + (float)v1[j];
  }
  if (i < end) {
    const int s = ssrc[i];
    const h16x8 v = *(const h16x8*)(h2h + (size_t)s * 128 + col);
#pragma unroll
    for (int j = 0; j < 8; ++j) acc[j] += (float)v[j];
  }
  short8 h8, l8;
#pragma unroll
  for (int j = 0; j < 8; ++j) {
    const unsigned short hi = bf16rne(acc[j]);
    h8[j] = (short)hi;
    l8[j] = (short)bf16rne(acc[j] - bf16tof(hi));
  }
  const int T = node >> 6, r = node & 63;
  const int Mt = r >> 4, r16 = r & 15, ks = c >> 2, kg = c & 3;
  const size_t fe = (size_t)T * 16384 + (size_t)((Mt * 4 + ks) * 64 + kg * 16 + r16) * 8;
  *(short8*)(Hhi + fe) = h8;
  *(short8*)(Hlo + fe) = l8;
}

// ---------------- fused output MLP, split-bf16 MFMA (verified R4/R14) ------
__global__ __launch_bounds__(256) void fused_out_mfma(
    const unsigned short* __restrict__ Ahi, const unsigned short* __restrict__ Alo,
    const unsigned short* __restrict__ FW0h, const unsigned short* __restrict__ FW0l,
    const unsigned short* __restrict__ PW0h, const unsigned short* __restrict__ PW0l,
    const unsigned short* __restrict__ WC1h, const unsigned short* __restrict__ WC1l,
    const unsigned short* __restrict__ WC2h, const unsigned short* __restrict__ WC2l,
    const float* __restrict__ bsum, const float* __restrict__ bc,
    float* __restrict__ out, int nrows)
{
  __shared__ __attribute__((aligned(16))) char smem[65536];
  const int tid  = threadIdx.x;
  const int row0 = blockIdx.x * 64;

  {
    const size_t tb = (size_t)blockIdx.x * 16384;
#pragma unroll
    for (int it = 0; it < 4; ++it) {
      const int i = it * 256 + tid;        // 1024 chunks of 16B
      *(short8*)(smem + i * 16)         = *(const short8*)(Ahi + tb + (size_t)i * 8);
      *(short8*)(smem + 16384 + i * 16) = *(const short8*)(Alo + tb + (size_t)i * 8);
    }
  }
  __syncthreads();

  const int w = tid >> 6, lane = tid & 63;
  union U8 { short8 s; unsigned int u[4]; };

  f32x4 oacc[4][4] = {};

  for (int sc = 0; sc < 4; ++sc) {
    f32x4 zacc[4][2] = {};
#pragma unroll
    for (int ks = 0; ks < 4; ++ks) {
      short8 w0h[2], w0l[2], p0h[2], p0l[2];
#pragma unroll
      for (int nt = 0; nt < 2; ++nt) {
        const int t = w * 8 + sc * 2 + nt;
        const size_t ofs = (size_t)(t * 4 + ks) * 512 + lane * 8;
        w0h[nt] = *(const short8*)(FW0h + ofs);
        w0l[nt] = *(const short8*)(FW0l + ofs);
        p0h[nt] = *(const short8*)(PW0h + ofs);
        p0l[nt] = *(const short8*)(PW0l + ofs);
      }
#pragma unroll
      for (int Mt = 0; Mt < 4; ++Mt) {
        const int fb = ((Mt * 4 + ks) * 64 + lane) * 16;
        U8 hh, hl, rh, rl;
        hh.s = *(const short8*)(smem + fb);
        hl.s = *(const short8*)(smem + 16384 + fb);
#pragma unroll
        for (int u = 0; u < 4; ++u) {
          unsigned int msk = ((hh.u[u] & 0x80008000u) >> 15) * 0xFFFFu;
          rh.u[u] = hh.u[u] & ~msk;
          rl.u[u] = hl.u[u] & ~msk;
        }
#pragma unroll
        for (int nt = 0; nt < 2; ++nt) {
          f32x4 a = zacc[Mt][nt];
          a = __builtin_amdgcn_mfma_f32_16x16x32_bf16(rh.s, w0h[nt], a, 0, 0, 0);
          a = __builtin_amdgcn_mfma_f32_16x16x32_bf16(rh.s, w0l[nt], a, 0, 0, 0);
          a = __builtin_amdgcn_mfma_f32_16x16x32_bf16(rl.s, w0h[nt], a, 0, 0, 0);
          a = __builtin_amdgcn_mfma_f32_16x16x32_bf16(hh.s, p0h[nt], a, 0, 0, 0);
          a = __builtin_amdgcn_mfma_f32_16x16x32_bf16(hh.s, p0l[nt], a, 0, 0, 0);
          a = __builtin_amdgcn_mfma_f32_16x16x32_bf16(hl.s, p0h[nt], a, 0, 0, 0);
          zacc[Mt][nt] = a;
        }
      }
    }
    const float bs0 = bsum[w * 128 + sc * 32 + (lane & 15)];
    const float bs1 = bsum[w * 128 + sc * 32 + 16 + (lane & 15)];
#pragma unroll
    for (int Mt = 0; Mt < 4; ++Mt) {
#pragma unroll
      for (int nt = 0; nt < 2; ++nt) {
        const float bs = nt ? bs1 : bs0;
        const int kg = nt * 2 + ((lane >> 3) & 1);
        const int eb = (lane & 7) * 2;
#pragma unroll
        for (int reg = 0; reg < 4; ++reg) {
          const float zv = fmaxf(zacc[Mt][nt][reg] + bs, 0.f);
          const unsigned short zhi = bf16rne(zv);
          const unsigned short zlo = bf16rne(zv - bf16tof(zhi));
          const int r16 = (lane >> 4) * 4 + reg;
          const int fb = ((w * 4 + Mt) * 64 + kg * 16 + r16) * 16 + eb;
          *(unsigned short*)(smem + 32768 + fb) = zhi;
          *(unsigned short*)(smem + 49152 + fb) = zlo;
        }
      }
    }
    asm volatile("s_waitcnt lgkmcnt(0)" ::: "memory");
    const int s2 = w * 4 + sc;
    short8 c1h[4], c1l[4];
#pragma unroll
    for (int t2 = 0; t2 < 4; ++t2) {
      const size_t ofs = (size_t)(t2 * 16 + s2) * 512 + lane * 8;
      c1h[t2] = *(const short8*)(WC1h + ofs);
      c1l[t2] = *(const short8*)(WC1l + ofs);
    }
#pragma unroll
    for (int Mt = 0; Mt < 4; ++Mt) {
      const int fb = ((w * 4 + Mt) * 64 + lane) * 16;
      short8 zh8 = *(const short8*)(smem + 32768 + fb);
      short8 zl8 = *(const short8*)(smem + 49152 + fb);
#pragma unroll
      for (int t2 = 0; t2 < 4; ++t2) {
        f32x4 a = oacc[Mt][t2];
        a = __builtin_amdgcn_mfma_f32_16x16x32_bf16(zh8, c1h[t2], a, 0, 0, 0);
        a = __builtin_amdgcn_mfma_f32_16x16x32_bf16(zh8, c1l[t2], a, 0, 0, 0);
        a = __builtin_amdgcn_mfma_f32_16x16x32_bf16(zl8, c1h[t2], a, 0, 0, 0);
        oacc[Mt][t2] = a;
      }
    }
  }

  {
    short8 c2h[4], c2l[4];
#pragma unroll
    for (int t = 0; t < 4; ++t) {
      const size_t ofs = (size_t)(t * 4 + w) * 512 + lane * 8;
      c2h[t] = *(const short8*)(WC2h + ofs);
      c2l[t] = *(const short8*)(WC2l + ofs);
    }
#pragma unroll
    for (int Mt = 0; Mt < 4; ++Mt) {
      const int fb = ((Mt * 4 + w) * 64 + lane) * 16;
      short8 hh = *(const short8*)(smem + fb);
      short8 hl = *(const short8*)(smem + 16384 + fb);
#pragma unroll
      for (int t = 0; t < 4; ++t) {
        f32x4 a = oacc[Mt][t];
        a = __builtin_amdgcn_mfma_f32_16x16x32_bf16(hh, c2h[t], a, 0, 0, 0);
        a = __builtin_amdgcn_mfma_f32_16x16x32_bf16(hh, c2l[t], a, 0, 0, 0);
        a = __builtin_amdgcn_mfma_f32_16x16x32_bf16(hl, c2h[t], a, 0, 0, 0);
        oacc[Mt][t] = a;
      }
    }
  }

  __syncthreads();
  float* red = (float*)smem;
#pragma unroll
  for (int Mt = 0; Mt < 4; ++Mt)
#pragma unroll
    for (int Nt = 0; Nt < 4; ++Nt)
#pragma unroll
      for (int reg = 0; reg < 4; ++reg) {
        const int row = Mt * 16 + (lane >> 4) * 4 + reg;
        const int col = Nt * 16 + (lane & 15);
        red[(w * 64 + row) * 64 + col] = oacc[Mt][Nt][reg];
      }
  __syncthreads();
  {
    const int c4 = (tid & 15) * 4;
    const int rb = tid >> 4;
    const float4 bcv = *(const float4*)(bc + c4);
#pragma unroll
    for (int rr = 0; rr < 4; ++rr) {
      const int r = rr * 16 + rb;
      const int gr = row0 + r;
      if (gr < nrows) {
        float4 s = bcv;
#pragma unroll
        for (int wv = 0; wv < 4; ++wv) {
          const float4 p = *(const float4*)&red[(wv * 64 + r) * 64 + c4];
          s.x += p.x; s.y += p.y; s.z += p.z; s.w += p.w;
        }
        *(float4*)(out + (size_t)gr * 64 + c4) = s;
      }
    }
  }
}

// ---------------------------------------------------------------------------
extern "C" void kernel_launch(void* const* d_in, const int* in_sizes, int n_in,
                              void* d_out, int out_size, void* d_ws, size_t ws_size,
                              hipStream_t stream) {
  const float* x    = (const float*)d_in[0];
  const int*   ei   = (const int*)d_in[1];   // [2][E] int32
  const float* mpW0 = (const float*)d_in[2];
  const float* mpb0 = (const float*)d_in[3];
  const float* mpW1 = (const float*)d_in[4];
  const float* mpb1 = (const float*)d_in[5];
  const float* mpW2 = (const float*)d_in[6];
  const float* mpb2 = (const float*)d_in[7];
  const float* fcW0 = (const float*)d_in[8];
  const float* fcb0 = (const float*)d_in[9];
  const float* fcW1 = (const float*)d_in[10];
  const float* fcb1 = (const float*)d_in[11];
  const float* pW0  = (const float*)d_in[12];
  const float* pb0  = (const float*)d_in[13];
  const float* pW1  = (const float*)d_in[14];
  const float* pb1  = (const float*)d_in[15];
  const float* outW = (const float*)d_in[16];
  const float* outb = (const float*)d_in[17];

  const int N = in_sizes[0] / 128;
  const int E = in_sizes[1] / 2;
  const int NB    = (N + 127) / 128;         // coarse buckets (<=1024)
  const int NBLK  = (E + CH - 1) / CH;       // P1/P3 blocks
  const int tiles = (N + 63) / 64;

  char* ws = (char*)d_ws;
  size_t off = 0;
  auto alloc = [&](size_t bytes) -> char* {
    char* p = ws + off;
    off += (bytes + 255) & ~(size_t)255;
    return p;
  };
  float* norm   = (float*)alloc((size_t)N * 4);
  int*   rowptr = (int*)alloc((size_t)(N + 1) * 4);
  int*   bcnt_t = (int*)alloc((size_t)NB * NBLK * 4);
  int*   bcnt_s = (int*)alloc((size_t)NB * NBLK * 4);
  int*   ofs_t  = (int*)alloc((size_t)NB * NBLK * 4);
  int*   ofs_s  = (int*)alloc((size_t)NB * NBLK * 4);
  int*   tot_t  = (int*)alloc((size_t)NB * 4);
  int*   tot_s  = (int*)alloc((size_t)NB * 4);
  int*   barr_t = (int*)alloc((size_t)(NB + 1) * 4);
  int*   barr_s = (int*)alloc((size_t)(NB + 1) * 4);
  int*   ssrc   = (int*)alloc((size_t)E * 4);
  int*   ssbin  = (int*)alloc((size_t)E * 4);
  unsigned long long* sorted = (unsigned long long*)alloc((size_t)E * 8);
  _Float16* h2h = (_Float16*)alloc((size_t)N * 128 * 2);
  unsigned short* Hhi = (unsigned short*)alloc((size_t)tiles * 16384 * 2);
  unsigned short* Hlo = (unsigned short*)alloc((size_t)tiles * 16384 * 2);
  float* Wc1    = (float*)alloc(512 * 64 * 4);
  float* Wc2    = (float*)alloc(128 * 64 * 4);
  float* bc     = (float*)alloc(64 * 4);
  unsigned short* FW0h = (unsigned short*)alloc(65536 * 2);
  unsigned short* FW0l = (unsigned short*)alloc(65536 * 2);
  unsigned short* PW0h = (unsigned short*)alloc(65536 * 2);
  unsigned short* PW0l = (unsigned short*)alloc(65536 * 2);
  unsigned short* WC1h = (unsigned short*)alloc(32768 * 2);
  unsigned short* WC1l = (unsigned short*)alloc(32768 * 2);
  unsigned short* WC2h = (unsigned short*)alloc(8192 * 2);
  unsigned short* WC2l = (unsigned short*)alloc(8192 * 2);
  float* bsum   = (float*)alloc(512 * 4);
  unsigned short* M0h = (unsigned short*)alloc(16384 * 2);
  unsigned short* M0l = (unsigned short*)alloc(16384 * 2);
  unsigned short* M1h = (unsigned short*)alloc(16384 * 2);
  unsigned short* M1l = (unsigned short*)alloc(16384 * 2);
  unsigned short* M2h = (unsigned short*)alloc(16384 * 2);
  unsigned short* M2l = (unsigned short*)alloc(16384 * 2);
  // total ~= 125 MiB

  const int scblocks = (NB + 3) / 4;

  p1_kernel<<<NBLK, 256, 0, stream>>>(ei, E, NB, NBLK, bcnt_t, bcnt_s);
  scan_tot2<<<scblocks * 2, 256, 0, stream>>>(bcnt_t, bcnt_s, tot_t, tot_s,
                                              NBLK, NB, scblocks);
  scan_base2<<<2, 1024, 0, stream>>>(tot_t, tot_s, barr_t, barr_s, NB, E, rowptr, N);
  scan_ofs2<<<scblocks * 2, 256, 0, stream>>>(bcnt_t, bcnt_s, barr_t, barr_s,
                                              ofs_t, ofs_s, NBLK, NB, scblocks);
  p3_kernel<<<NBLK, 256, 0, stream>>>(ei, E, NB, NBLK, ofs_t, ofs_s, sorted, ssbin);
  p4m_kernel<<<NB * 2, 256, 0, stream>>>(sorted, barr_t, rowptr, ssrc,
                                         ssbin, barr_s, norm, N, NB);
  combine_kernel<<<(512 * 64 + 128 * 64 + 64 + 255) / 256, 256, 0, stream>>>(
      fcW1, fcb1, pW1, pb1, outW, outb, Wc1, Wc2, bc);
  convw_kernel<<<(107008 + 3 * 16384 + 255) / 256, 256, 0, stream>>>(
      fcW0, pW0, Wc1, Wc2, fcb0, pb0, mpW0, mpW1, mpW2,
      FW0h, FW0l, PW0h, PW0l, WC1h, WC1l, WC2h, WC2l, bsum,
      M0h, M0l, M1h, M1l, M2h, M2l);

  const int gx = tiles;
  const int ablocks = (N + 15) / 16;   // 4 waves/block, 4 nodes/wave

  mp_gemm_mfma<<<gx, 256, 0, stream>>>(x, M0h, M0l, mpb0, norm, h2h, N);
  agg_kernel<<<ablocks, 256, 0, stream>>>(h2h, rowptr, ssrc, Hhi, Hlo, N);
  mp_gemm_pre<<<gx, 256, 0, stream>>>(Hhi, Hlo, M1h, M1l, mpb1, norm, h2h, N);
  agg_kernel<<<ablocks, 256, 0, stream>>>(h2h, rowptr, ssrc, Hhi, Hlo, N);
  mp_gemm_pre<<<gx, 256, 0, stream>>>(Hhi, Hlo, M2h, M2l, mpb2, norm, h2h, N);
  agg_kernel<<<ablocks, 256, 0, stream>>>(h2h, rowptr, ssrc, Hhi, Hlo, N);

  fused_out_mfma<<<gx, 256, 0, stream>>>(
      Hhi, Hlo, FW0h, FW0l, PW0h, PW0l, WC1h, WC1l, WC2h, WC2l, bsum, bc,
      (float*)d_out, N);
}